// Round 5
// baseline (338.602 us; speedup 1.0000x reference)
//
#include <hip/hip_runtime.h>

#define NB 8
#define NS 2048
#define NH 768
#define NPOS (NB*NS)

typedef _Float16 half8 __attribute__((ext_vector_type(8)));
typedef float floatx4 __attribute__((ext_vector_type(4)));

// async global->LDS, 16B per lane; LDS dest must be wave-uniform base + lane*16
#define GLOAD_LDS16(gp, lp) __builtin_amdgcn_global_load_lds( \
  (const __attribute__((address_space(1))) unsigned int*)(gp), \
  (__attribute__((address_space(3))) unsigned int*)(lp), 16, 0, 0)

// ---------------- Kernel Epre: pre-tile E into swizzled f16 hi/lo tiles ----------------
// Tile (b, hb, tc) = [192 h][32 t], 12288 shorts (24 KB): hi image [0,6144),
// lo image [6144,12288); within each: off = h2*32 + ((q2^((h2>>1)&3))*8).
// f16 split: hi = f16(e) (RTN), lo = f16(e - hi) -> 22-bit effective mantissa.
// Block (0,0,0) threads 0..15 additionally build V = U*diag((-i)^popc) (tiny).
__global__ __launch_bounds__(384) void epre_kernel(
    const float* __restrict__ E, const float* __restrict__ wts,
    float* __restrict__ Vre, float* __restrict__ Vim,
    unsigned short* __restrict__ ET) {
  int tc = blockIdx.x, hb = blockIdx.y, b = blockIdx.z;
  int tid = threadIdx.x;

  if (tc == 0 && hb == 0 && b == 0 && tid < 16) {
    int j = tid;
    float ar[16], ai[16];
#pragma unroll
    for (int i = 0; i < 16; i++) { ar[i] = (i == j) ? 1.f : 0.f; ai[i] = 0.f; }
#pragma unroll
    for (int l = 0; l < 2; l++) {
#pragma unroll
      for (int q = 0; q < 4; q++) {
        float phi = wts[(l*4+q)*3+0];
        float th  = wts[(l*4+q)*3+1];
        float om  = wts[(l*4+q)*3+2];
        float ct = cosf(0.5f*th), st = sinf(0.5f*th);
        float sm = 0.5f*(phi+om), df = 0.5f*(phi-om);
        float cs = cosf(sm), ss = sinf(sm), cd = cosf(df), sd = sinf(df);
        float Ar =  cs*ct, Ai = -ss*ct;
        float Br = -cd*st, Bi = -sd*st;
        float Cr =  cd*st, Ci = -sd*st;
        float Dr =  cs*ct, Di =  ss*ct;
        int pb = 1 << (3-q);
#pragma unroll
        for (int b0 = 0; b0 < 16; b0++) {
          if (b0 & pb) continue;
          int b1 = b0 | pb;
          float xr = ar[b0], xi = ai[b0], yr = ar[b1], yi = ai[b1];
          ar[b0] = Ar*xr - Ai*xi + Br*yr - Bi*yi;
          ai[b0] = Ar*xi + Ai*xr + Br*yi + Bi*yr;
          ar[b1] = Cr*xr - Ci*xi + Dr*yr - Di*yi;
          ai[b1] = Cr*xi + Ci*xr + Dr*yi + Di*yr;
        }
      }
      const int r = (l == 0) ? 1 : 2;
#pragma unroll
      for (int i2 = 0; i2 < 4; i2++) {
        int cb = 1 << (3-i2);
        int tb = 1 << (3-((i2+r)&3));
#pragma unroll
        for (int b0 = 0; b0 < 16; b0++) {
          if ((b0 & cb) && !(b0 & tb)) {
            int b1 = b0 | tb;
            float tr = ar[b0], ti = ai[b0];
            ar[b0] = ar[b1]; ai[b0] = ai[b1];
            ar[b1] = tr;     ai[b1] = ti;
          }
        }
      }
    }
    int pc = __popc((unsigned)j) & 3;
#pragma unroll
    for (int i = 0; i < 16; i++) {
      float vr = ar[i], vi = ai[i], orr, oi;
      if      (pc == 0) { orr =  vr; oi =  vi; }
      else if (pc == 1) { orr =  vi; oi = -vr; }
      else if (pc == 2) { orr = -vr; oi = -vi; }
      else              { orr = -vi; oi =  vr; }
      Vre[i*16+j] = orr;
      Vim[i*16+j] = oi;
    }
  }

  size_t tbase = ((size_t)((b*4 + hb)*64 + tc)) * 12288;
  const float* Eb = E + (size_t)b*NS*NH + (size_t)tc*32*NH + hb*192;
#pragma unroll
  for (int u = 0; u < 2; u++) {
    int unit = tid + 384*u;          // 0..767
    int q2 = unit / 192, h2 = unit % 192;
    unsigned hi4[4], lo4[4];
#pragma unroll
    for (int jp = 0; jp < 4; jp++) {
      float ea = Eb[(size_t)(q2*8 + 2*jp    )*NH + h2];
      float eb = Eb[(size_t)(q2*8 + 2*jp + 1)*NH + h2];
      _Float16 ha = (_Float16)ea, hb16 = (_Float16)eb;
      float la = ea - (float)ha, lb = eb - (float)hb16;
      unsigned uha = __builtin_bit_cast(unsigned short, ha);
      unsigned uhb = __builtin_bit_cast(unsigned short, hb16);
      unsigned ula = __builtin_bit_cast(unsigned short, (_Float16)la);
      unsigned ulb = __builtin_bit_cast(unsigned short, (_Float16)lb);
      hi4[jp] = uha | (uhb << 16);
      lo4[jp] = ula | (ulb << 16);
    }
    int off = h2*32 + ((q2 ^ ((h2>>1)&3))*8);
    *(uint4*)&ET[tbase + off]        = make_uint4(hi4[0],hi4[1],hi4[2],hi4[3]);
    *(uint4*)&ET[tbase + 6144 + off] = make_uint4(lo4[0],lo4[1],lo4[2],lo4[3]);
  }
}

// ---------------- Kernel B: Q/K projection + VQC evaluation ----------------
__global__ __launch_bounds__(256) void proj_vqc_kernel(
    const float* __restrict__ E, const float* __restrict__ Wq, const float* __restrict__ bq,
    const float* __restrict__ Wk, const float* __restrict__ bk,
    const float* __restrict__ Vre, const float* __restrict__ Vim,
    float* __restrict__ Qv, float* __restrict__ Kv) {
  __shared__ __align__(16) float WqL[768*4];
  __shared__ __align__(16) float WkL[768*4];
  __shared__ float Vsh[2][16*17];
  int tid = threadIdx.x;
  for (int idx = tid; idx < 768*4; idx += 256) {
    int e = idx >> 2, w = idx & 3;
    WqL[e*4+w] = Wq[w*768+e];
    WkL[e*4+w] = Wk[w*768+e];
  }
  if (tid < 256) {
    int i = tid >> 4, jj = tid & 15;
    Vsh[0][i*17+jj] = Vre[tid];
    Vsh[1][i*17+jj] = Vim[tid];
  }
  __syncthreads();
  float bqr0=bq[0], bqr1=bq[1], bqr2=bq[2], bqr3=bq[3];
  float bkr0=bk[0], bkr1=bk[1], bkr2=bk[2], bkr3=bk[3];
  int lane = tid & 63;
  int wid  = blockIdx.x*4 + (tid >> 6);
  int nw   = gridDim.x*4;
  int grp  = lane >> 4;
  int i    = lane & 15;
  for (int pos = wid; pos < NPOS; pos += nw) {
    const float* er = E + (size_t)pos*768;
    float pq[4] = {0.f,0.f,0.f,0.f};
    float pk[4] = {0.f,0.f,0.f,0.f};
#pragma unroll
    for (int k2 = 0; k2 < 3; k2++) {
      float4 ev = *(const float4*)(er + lane*4 + 256*k2);
#pragma unroll
      for (int jj = 0; jj < 4; jj++) {
        int e = lane*4 + 256*k2 + jj;
        float evs = (jj==0) ? ev.x : (jj==1) ? ev.y : (jj==2) ? ev.z : ev.w;
        float4 wq4 = *(const float4*)&WqL[e*4];
        float4 wk4 = *(const float4*)&WkL[e*4];
        pq[0] += evs*wq4.x; pq[1] += evs*wq4.y; pq[2] += evs*wq4.z; pq[3] += evs*wq4.w;
        pk[0] += evs*wk4.x; pk[1] += evs*wk4.y; pk[2] += evs*wk4.z; pk[3] += evs*wk4.w;
      }
    }
    float part[8];
#pragma unroll
    for (int w = 0; w < 8; w++) {
      float v = (w < 4) ? pq[w] : pk[w-4];
      v += __shfl_xor(v, 32); v += __shfl_xor(v, 16); v += __shfl_xor(v, 8);
      v += __shfl_xor(v, 4);  v += __shfl_xor(v, 2);  v += __shfl_xor(v, 1);
      part[w] = v;
    }
    if (grp < 2) {
      float a0,a1,a2,a3;
      if (grp == 0) { a0=part[0]+bqr0; a1=part[1]+bqr1; a2=part[2]+bqr2; a3=part[3]+bqr3; }
      else          { a0=part[4]+bkr0; a1=part[5]+bkr1; a2=part[6]+bkr2; a3=part[7]+bkr3; }
      float c0=cosf(0.5f*a0), s0=sinf(0.5f*a0);
      float c1=cosf(0.5f*a1), s1=sinf(0.5f*a1);
      float c2=cosf(0.5f*a2), s2=sinf(0.5f*a2);
      float c3=cosf(0.5f*a3), s3=sinf(0.5f*a3);
      float m[16];
#pragma unroll
      for (int j2 = 0; j2 < 16; j2++) {
        float f0 = (j2 & 8) ? s0 : c0;
        float f1 = (j2 & 4) ? s1 : c1;
        float f2 = (j2 & 2) ? s2 : c2;
        float f3 = (j2 & 1) ? s3 : c3;
        m[j2] = f0*f1*f2*f3;
      }
      float re = 0.f, im = 0.f;
#pragma unroll
      for (int j2 = 0; j2 < 16; j2++) {
        re += Vsh[0][i*17+j2]*m[j2];
        im += Vsh[1][i*17+j2]*m[j2];
      }
      float pr = re*re + im*im;
      float r0 = (i & 8) ? -pr : pr;
      float r1 = (i & 4) ? -pr : pr;
      float r2 = (i & 2) ? -pr : pr;
      float r3 = (i & 1) ? -pr : pr;
#pragma unroll
      for (int off = 8; off >= 1; off >>= 1) {
        r0 += __shfl_xor(r0, off);
        r1 += __shfl_xor(r1, off);
        r2 += __shfl_xor(r2, off);
        r3 += __shfl_xor(r3, off);
      }
      if (i == 0) {
        float* dst = (grp == 0 ? Qv : Kv) + (size_t)pos*4;
        dst[0]=r0; dst[1]=r1; dst[2]=r2; dst[3]=r3;
      }
    }
  }
}

// ---------------- Kernel C: fused attention, 128s x 384h (2 hblks merged), 8 waves ----------------
// P in-kernel at only 2x redundancy (was 4x in r2, or a 67MB HBM round-trip in r3's pgen).
// Grid 256 = (2 hp x 16 sblk x 8 b) -> exactly 1 block/CU; b = bid&7 keeps one batch
// per XCD (L2-hot E tiles, FETCH ~ one pass over ET).
// Per chunk: DMA two 24KB E tiles (6 x global_load_lds), 8 exp/thread P-gen into
// double-buffered sA, 16 ds_read_b128 + 48 MFMA per wave (wave tile 64s x 96h).
// LDS: sA 2x8KB + sB 2x48KB + dfin 0.5KB = 112.5 KB -> 1 block/CU, 8 waves.
// r5 fix vs r4: dma_chunk second-tile SOURCE offsets are {0,4096,8192} within t1
// (r4 mistakenly reused the 16384/20480 DEST offsets as source -> read chunk ci+1).
#define TKC 32

__global__ __launch_bounds__(512, 2) void attn_kernel(
    const unsigned short* __restrict__ ET, const float* __restrict__ Qv,
    const float* __restrict__ Kv, float* __restrict__ out) {
  int bid  = blockIdx.x;
  int b    = bid & 7;        // same-b blocks land on same XCD
  int r    = bid >> 3;       // 0..31
  int sblk = r & 15;
  int hp   = r >> 4;         // 0..1 (covers hb = hp*2, hp*2+1)
  int tid  = threadIdx.x;
  int lane = tid & 63;
  int w    = tid >> 6;       // 0..7

  __shared__ __align__(16) unsigned short sA[2][4096];    // f16 P, double-buffered
  __shared__ __align__(16) unsigned short sB[2][24576];   // two E tiles: [0,12288) hb0, [12288,24576) hb1
  __shared__ float dfin[128];

  const unsigned short* tEh = ET + ((size_t)((b*4 + hp*2)*64)) * 12288;

  // ---- P-gen mapping: 512 threads cover 128 s x 4 slots; 8 P values each ----
  int sPg = tid >> 2, slotg = tid & 3;
  int qg  = slotg ^ ((sPg >> 1) & 3);          // logical t-octet stored at physical slot slotg
  int offA = sPg*32 + slotg*8;
  float4 qv = *(const float4*)&Qv[((size_t)(b*NS + sblk*128) + sPg)*4];
  const float* kvbase = Kv + (size_t)b*NS*4 + (size_t)qg*8*4;
  float den_acc = 0.f;

  int sh = w & 1, hh = w >> 1;   // wave tile: 64 s x 96 h
  floatx4 acc[4][6];
#pragma unroll
  for (int i = 0; i < 4; i++)
#pragma unroll
    for (int jt = 0; jt < 6; jt++) acc[i][jt] = floatx4{0.f,0.f,0.f,0.f};

  int m16 = lane & 15, q16 = lane >> 4;
  int cidx = (q16 ^ ((m16 >> 1) & 3)) * 8;   // swizzled chunk offset for frag reads
  int t16 = tid * 8;                          // 8 shorts = 16 B per thread per DMA round
  int hbase = (hh >> 1)*12288 + (hh & 1)*3072;  // tile sel + 96-row offset (shorts)

  auto kvload = [&](int ci, float4* kvr) {
    const float* kvp = kvbase + (size_t)ci*128;   // rows ci*32 + qg*8 + j
#pragma unroll
    for (int j = 0; j < 8; j++) kvr[j] = *(const float4*)(kvp + j*4);
  };

  auto pcompute = [&](const float4* kvr) -> uint4 {
    unsigned h4[4];
    float dsum = 0.f;
#pragma unroll
    for (int jp = 0; jp < 4; jp++) {
      float4 ka = kvr[2*jp];
      float4 kb = kvr[2*jp+1];
      float arga = qv.x*ka.x + qv.y*ka.y + qv.z*ka.z + qv.w*ka.w;
      float argb = qv.x*kb.x + qv.y*kb.y + qv.z*kb.z + qv.w*kb.w;
      float pa = __expf(arga), pb = __expf(argb);
      dsum += pa + pb;
      unsigned ua = (unsigned)__builtin_bit_cast(unsigned short, (_Float16)pa);
      unsigned ub = (unsigned)__builtin_bit_cast(unsigned short, (_Float16)pb);
      h4[jp] = ua | (ub << 16);
    }
    den_acc += dsum;
    return make_uint4(h4[0], h4[1], h4[2], h4[3]);
  };

  auto dma_chunk = [&](int ci, int nb) {
    const unsigned short* t0 = tEh + (size_t)ci*12288;       // tile (b, hp*2,   ci)
    const unsigned short* t1 = t0 + (size_t)64*12288;        // tile (b, hp*2+1, ci)
    unsigned short* d = &sB[nb][0];
    GLOAD_LDS16(t0 + t16,        d + t16);
    GLOAD_LDS16(t0 + 4096 + t16, d + 4096 + t16);
    GLOAD_LDS16(t0 + 8192 + t16, d + 8192 + t16);
    GLOAD_LDS16(t1 + t16,        d + 12288 + t16);
    GLOAD_LDS16(t1 + 4096 + t16, d + 16384 + t16);
    GLOAD_LDS16(t1 + 8192 + t16, d + 20480 + t16);
  };

  // ---- prologue: kv(0), DMA E(0) -> sB[0], P(0) -> sA[0] ----
  {
    float4 kvr[8];
    kvload(0, kvr);
    dma_chunk(0, 0);
    uint4 ph = pcompute(kvr);
    *(uint4*)&sA[0][offA] = ph;
  }

  // ---- main loop: ONE barrier per chunk ----
  for (int ci = 0; ci < 64; ci++) {
    int cb = ci & 1;
    __syncthreads();   // DMA(ci) drained; sA[cb] P visible; prev MFMA reads retired
    if (ci < 63) {
      float4 kvr[8];
      kvload(ci+1, kvr);
      dma_chunk(ci+1, cb^1);
      uint4 ph = pcompute(kvr);
      *(uint4*)&sA[cb^1][offA] = ph;
    }
    // MFMA: wave (sh,hh) computes 64x96 via 4x6 tiles of 16x16x32, 2 passes
    const unsigned short* sAc = &sA[cb][0];
    const unsigned short* sBc = &sB[cb][0];
    half8 a[4];
#pragma unroll
    for (int i = 0; i < 4; i++) {
      int srow = sh*64 + i*16 + m16;
      a[i] = __builtin_bit_cast(half8, *(const uint4*)&sAc[srow*TKC + cidx]);
    }
#pragma unroll
    for (int jt = 0; jt < 6; jt++) {
      int ro = hbase + (jt*16 + m16)*TKC + cidx;
      half8 bh_ = __builtin_bit_cast(half8, *(const uint4*)&sBc[ro]);
      half8 bl_ = __builtin_bit_cast(half8, *(const uint4*)&sBc[ro + 6144]);
#pragma unroll
      for (int i = 0; i < 4; i++) {
        acc[i][jt] = __builtin_amdgcn_mfma_f32_16x16x32_f16(a[i], bl_, acc[i][jt], 0, 0, 0);
        acc[i][jt] = __builtin_amdgcn_mfma_f32_16x16x32_f16(a[i], bh_, acc[i][jt], 0, 0, 0);
      }
    }
  }

  // --- denominator reduce: 4 slots per s are 4 consecutive lanes ---
  {
    float v = den_acc;
    v += __shfl_xor(v, 1);
    v += __shfl_xor(v, 2);
    if (slotg == 0) dfin[sPg] = v;
  }
  __syncthreads();

  // --- epilogue: C/D layout col=lane&15, row=(lane>>4)*4+reg; scale by 1/den ---
  float* ob = out + ((size_t)(b*NS + sblk*128))*NH + hp*384;
#pragma unroll
  for (int i = 0; i < 4; i++) {
#pragma unroll
    for (int reg = 0; reg < 4; reg++) {
      int row = q16*4 + reg;
      int s_loc = sh*64 + i*16 + row;
      float invd = 1.0f / dfin[s_loc];
#pragma unroll
      for (int jt = 0; jt < 6; jt++) {
        int h_loc = hh*96 + jt*16 + m16;
        ob[(size_t)s_loc*NH + h_loc] = acc[i][jt][reg] * invd;
      }
    }
  }
}

extern "C" void kernel_launch(void* const* d_in, const int* in_sizes, int n_in,
                              void* d_out, int out_size, void* d_ws, size_t ws_size,
                              hipStream_t stream) {
  const float* E   = (const float*)d_in[0];
  const float* Wq  = (const float*)d_in[1];
  const float* bq  = (const float*)d_in[2];
  const float* Wk  = (const float*)d_in[3];
  const float* bk  = (const float*)d_in[4];
  const float* wts = (const float*)d_in[5];
  float* ws  = (float*)d_ws;
  float* Vre = ws;                       // 256 f
  float* Vim = ws + 256;                 // 256 f
  float* Qv  = ws + 512;                 // NPOS*4 f
  float* Kv  = Qv + (size_t)NPOS*4;      // NPOS*4 f
  unsigned short* ET = (unsigned short*)(Kv + (size_t)NPOS*4);  // 50.3 MB
  float* out = (float*)d_out;

  epre_kernel<<<dim3(64, 4, 8), 384, 0, stream>>>(E, wts, Vre, Vim, ET);
  proj_vqc_kernel<<<1024, 256, 0, stream>>>(E, Wq, bq, Wk, bk, Vre, Vim, Qv, Kv);
  attn_kernel<<<dim3(256), 512, 0, stream>>>(ET, Qv, Kv, out);
}

// Round 6
// 277.515 us; speedup vs baseline: 1.2201x; 1.2201x over previous
//
#include <hip/hip_runtime.h>

#define NB 8
#define NS 2048
#define NH 768
#define NPOS (NB*NS)

typedef _Float16 half8 __attribute__((ext_vector_type(8)));
typedef float floatx4 __attribute__((ext_vector_type(4)));

// async global->LDS, 16B per lane; LDS dest must be wave-uniform base + lane*16
#define GLOAD_LDS16(gp, lp) __builtin_amdgcn_global_load_lds( \
  (const __attribute__((address_space(1))) unsigned int*)(gp), \
  (__attribute__((address_space(3))) unsigned int*)(lp), 16, 0, 0)

// ---------------- Kernel Epre: pre-tile E into swizzled f16 hi/lo tiles ----------------
// Tile (b, hb, tc) = [192 h][32 t], 12288 shorts (24 KB): hi image [0,6144),
// lo image [6144,12288); within each: off = h2*32 + ((q2^((h2>>1)&3))*8).
// f16 split: hi = f16(e) (RTN), lo = f16(e - hi) -> 22-bit effective mantissa.
// Block (0,0,0) threads 0..15 additionally build V = U*diag((-i)^popc) (tiny).
__global__ __launch_bounds__(384) void epre_kernel(
    const float* __restrict__ E, const float* __restrict__ wts,
    float* __restrict__ Vre, float* __restrict__ Vim,
    unsigned short* __restrict__ ET) {
  int tc = blockIdx.x, hb = blockIdx.y, b = blockIdx.z;
  int tid = threadIdx.x;

  if (tc == 0 && hb == 0 && b == 0 && tid < 16) {
    int j = tid;
    float ar[16], ai[16];
#pragma unroll
    for (int i = 0; i < 16; i++) { ar[i] = (i == j) ? 1.f : 0.f; ai[i] = 0.f; }
#pragma unroll
    for (int l = 0; l < 2; l++) {
#pragma unroll
      for (int q = 0; q < 4; q++) {
        float phi = wts[(l*4+q)*3+0];
        float th  = wts[(l*4+q)*3+1];
        float om  = wts[(l*4+q)*3+2];
        float ct = cosf(0.5f*th), st = sinf(0.5f*th);
        float sm = 0.5f*(phi+om), df = 0.5f*(phi-om);
        float cs = cosf(sm), ss = sinf(sm), cd = cosf(df), sd = sinf(df);
        float Ar =  cs*ct, Ai = -ss*ct;
        float Br = -cd*st, Bi = -sd*st;
        float Cr =  cd*st, Ci = -sd*st;
        float Dr =  cs*ct, Di =  ss*ct;
        int pb = 1 << (3-q);
#pragma unroll
        for (int b0 = 0; b0 < 16; b0++) {
          if (b0 & pb) continue;
          int b1 = b0 | pb;
          float xr = ar[b0], xi = ai[b0], yr = ar[b1], yi = ai[b1];
          ar[b0] = Ar*xr - Ai*xi + Br*yr - Bi*yi;
          ai[b0] = Ar*xi + Ai*xr + Br*yi + Bi*yr;
          ar[b1] = Cr*xr - Ci*xi + Dr*yr - Di*yi;
          ai[b1] = Cr*xi + Ci*xr + Dr*yi + Di*yr;
        }
      }
      const int r = (l == 0) ? 1 : 2;
#pragma unroll
      for (int i2 = 0; i2 < 4; i2++) {
        int cb = 1 << (3-i2);
        int tb = 1 << (3-((i2+r)&3));
#pragma unroll
        for (int b0 = 0; b0 < 16; b0++) {
          if ((b0 & cb) && !(b0 & tb)) {
            int b1 = b0 | tb;
            float tr = ar[b0], ti = ai[b0];
            ar[b0] = ar[b1]; ai[b0] = ai[b1];
            ar[b1] = tr;     ai[b1] = ti;
          }
        }
      }
    }
    int pc = __popc((unsigned)j) & 3;
#pragma unroll
    for (int i = 0; i < 16; i++) {
      float vr = ar[i], vi = ai[i], orr, oi;
      if      (pc == 0) { orr =  vr; oi =  vi; }
      else if (pc == 1) { orr =  vi; oi = -vr; }
      else if (pc == 2) { orr = -vr; oi = -vi; }
      else              { orr = -vi; oi =  vr; }
      Vre[i*16+j] = orr;
      Vim[i*16+j] = oi;
    }
  }

  size_t tbase = ((size_t)((b*4 + hb)*64 + tc)) * 12288;
  const float* Eb = E + (size_t)b*NS*NH + (size_t)tc*32*NH + hb*192;
#pragma unroll
  for (int u = 0; u < 2; u++) {
    int unit = tid + 384*u;          // 0..767
    int q2 = unit / 192, h2 = unit % 192;
    unsigned hi4[4], lo4[4];
#pragma unroll
    for (int jp = 0; jp < 4; jp++) {
      float ea = Eb[(size_t)(q2*8 + 2*jp    )*NH + h2];
      float eb = Eb[(size_t)(q2*8 + 2*jp + 1)*NH + h2];
      _Float16 ha = (_Float16)ea, hb16 = (_Float16)eb;
      float la = ea - (float)ha, lb = eb - (float)hb16;
      unsigned uha = __builtin_bit_cast(unsigned short, ha);
      unsigned uhb = __builtin_bit_cast(unsigned short, hb16);
      unsigned ula = __builtin_bit_cast(unsigned short, (_Float16)la);
      unsigned ulb = __builtin_bit_cast(unsigned short, (_Float16)lb);
      hi4[jp] = uha | (uhb << 16);
      lo4[jp] = ula | (ulb << 16);
    }
    int off = h2*32 + ((q2 ^ ((h2>>1)&3))*8);
    *(uint4*)&ET[tbase + off]        = make_uint4(hi4[0],hi4[1],hi4[2],hi4[3]);
    *(uint4*)&ET[tbase + 6144 + off] = make_uint4(lo4[0],lo4[1],lo4[2],lo4[3]);
  }
}

// ---------------- Kernel B: Q/K projection + VQC evaluation ----------------
__global__ __launch_bounds__(256) void proj_vqc_kernel(
    const float* __restrict__ E, const float* __restrict__ Wq, const float* __restrict__ bq,
    const float* __restrict__ Wk, const float* __restrict__ bk,
    const float* __restrict__ Vre, const float* __restrict__ Vim,
    float* __restrict__ Qv, float* __restrict__ Kv) {
  __shared__ __align__(16) float WqL[768*4];
  __shared__ __align__(16) float WkL[768*4];
  __shared__ float Vsh[2][16*17];
  int tid = threadIdx.x;
  for (int idx = tid; idx < 768*4; idx += 256) {
    int e = idx >> 2, w = idx & 3;
    WqL[e*4+w] = Wq[w*768+e];
    WkL[e*4+w] = Wk[w*768+e];
  }
  if (tid < 256) {
    int i = tid >> 4, jj = tid & 15;
    Vsh[0][i*17+jj] = Vre[tid];
    Vsh[1][i*17+jj] = Vim[tid];
  }
  __syncthreads();
  float bqr0=bq[0], bqr1=bq[1], bqr2=bq[2], bqr3=bq[3];
  float bkr0=bk[0], bkr1=bk[1], bkr2=bk[2], bkr3=bk[3];
  int lane = tid & 63;
  int wid  = blockIdx.x*4 + (tid >> 6);
  int nw   = gridDim.x*4;
  int grp  = lane >> 4;
  int i    = lane & 15;
  for (int pos = wid; pos < NPOS; pos += nw) {
    const float* er = E + (size_t)pos*768;
    float pq[4] = {0.f,0.f,0.f,0.f};
    float pk[4] = {0.f,0.f,0.f,0.f};
#pragma unroll
    for (int k2 = 0; k2 < 3; k2++) {
      float4 ev = *(const float4*)(er + lane*4 + 256*k2);
#pragma unroll
      for (int jj = 0; jj < 4; jj++) {
        int e = lane*4 + 256*k2 + jj;
        float evs = (jj==0) ? ev.x : (jj==1) ? ev.y : (jj==2) ? ev.z : ev.w;
        float4 wq4 = *(const float4*)&WqL[e*4];
        float4 wk4 = *(const float4*)&WkL[e*4];
        pq[0] += evs*wq4.x; pq[1] += evs*wq4.y; pq[2] += evs*wq4.z; pq[3] += evs*wq4.w;
        pk[0] += evs*wk4.x; pk[1] += evs*wk4.y; pk[2] += evs*wk4.z; pk[3] += evs*wk4.w;
      }
    }
    float part[8];
#pragma unroll
    for (int w = 0; w < 8; w++) {
      float v = (w < 4) ? pq[w] : pk[w-4];
      v += __shfl_xor(v, 32); v += __shfl_xor(v, 16); v += __shfl_xor(v, 8);
      v += __shfl_xor(v, 4);  v += __shfl_xor(v, 2);  v += __shfl_xor(v, 1);
      part[w] = v;
    }
    if (grp < 2) {
      float a0,a1,a2,a3;
      if (grp == 0) { a0=part[0]+bqr0; a1=part[1]+bqr1; a2=part[2]+bqr2; a3=part[3]+bqr3; }
      else          { a0=part[4]+bkr0; a1=part[5]+bkr1; a2=part[6]+bkr2; a3=part[7]+bkr3; }
      float c0=cosf(0.5f*a0), s0=sinf(0.5f*a0);
      float c1=cosf(0.5f*a1), s1=sinf(0.5f*a1);
      float c2=cosf(0.5f*a2), s2=sinf(0.5f*a2);
      float c3=cosf(0.5f*a3), s3=sinf(0.5f*a3);
      float m[16];
#pragma unroll
      for (int j2 = 0; j2 < 16; j2++) {
        float f0 = (j2 & 8) ? s0 : c0;
        float f1 = (j2 & 4) ? s1 : c1;
        float f2 = (j2 & 2) ? s2 : c2;
        float f3 = (j2 & 1) ? s3 : c3;
        m[j2] = f0*f1*f2*f3;
      }
      float re = 0.f, im = 0.f;
#pragma unroll
      for (int j2 = 0; j2 < 16; j2++) {
        re += Vsh[0][i*17+j2]*m[j2];
        im += Vsh[1][i*17+j2]*m[j2];
      }
      float pr = re*re + im*im;
      float r0 = (i & 8) ? -pr : pr;
      float r1 = (i & 4) ? -pr : pr;
      float r2 = (i & 2) ? -pr : pr;
      float r3 = (i & 1) ? -pr : pr;
#pragma unroll
      for (int off = 8; off >= 1; off >>= 1) {
        r0 += __shfl_xor(r0, off);
        r1 += __shfl_xor(r1, off);
        r2 += __shfl_xor(r2, off);
        r3 += __shfl_xor(r3, off);
      }
      if (i == 0) {
        float* dst = (grp == 0 ? Qv : Kv) + (size_t)pos*4;
        dst[0]=r0; dst[1]=r1; dst[2]=r2; dst[3]=r3;
      }
    }
  }
}

// ---------------- Kernel Pgen: P = exp(Qv.Kv) f16 pre-swizzled tiles + row-sum ----------------
// P tile (b, sblk, tc) = 4096 shorts (8 KB), layout off = s*32 + ((q^((s>>1)&3))*8),
// i.e. exactly the attn A-operand swizzle. Each P computed ONCE.
// r6 change vs r3: grid x 8 (was 2) -> 1024 blocks = up to 4 blocks/CU (r3's 256-block
// launch was 1 block/CU and latency-bound at ~76us; r5 proved this family is
// occupancy-bound). Each block now covers 8 chunks; Den has 8 partials.
__global__ __launch_bounds__(512, 4) void pgen_kernel(
    const float* __restrict__ Qv, const float* __restrict__ Kv,
    unsigned short* __restrict__ P, float* __restrict__ Den) {
  int th = blockIdx.x, sblk = blockIdx.y, b = blockIdx.z;
  int tid = threadIdx.x;
  int s = tid >> 2, qq = tid & 3;
  int q = qq ^ ((s >> 1) & 3);
  float4 qv = *(const float4*)&Qv[((size_t)(b*NS + sblk*128) + s)*4];
  const float* Kvb = Kv + (size_t)b*NS*4;
  unsigned short* Pt = P + ((size_t)(b*16 + sblk))*64*4096;
  float den_acc = 0.f;
  for (int tc = th*8; tc < th*8 + 8; tc++) {
    const float* kvp = Kvb + ((size_t)tc*32 + q*8)*4;
    unsigned h4[4];
#pragma unroll
    for (int jp = 0; jp < 4; jp++) {
      float4 ka = *(const float4*)(kvp + 8*jp);
      float4 kb = *(const float4*)(kvp + 8*jp + 4);
      float arga = qv.x*ka.x + qv.y*ka.y + qv.z*ka.z + qv.w*ka.w;
      float argb = qv.x*kb.x + qv.y*kb.y + qv.z*kb.z + qv.w*kb.w;
      float pa = __expf(arga), pb = __expf(argb);
      den_acc += pa + pb;
      unsigned ua = (unsigned)__builtin_bit_cast(unsigned short, (_Float16)pa);
      unsigned ub = (unsigned)__builtin_bit_cast(unsigned short, (_Float16)pb);
      h4[jp] = ua | (ub << 16);
    }
    *(uint4*)&Pt[(size_t)tc*4096 + tid*8] = make_uint4(h4[0], h4[1], h4[2], h4[3]);
  }
  // per-s denominator partial: sum the 4 q-groups (adjacent lanes)
  float v = den_acc;
  v += __shfl_xor(v, 1);
  v += __shfl_xor(v, 2);
  if (qq == 0) {
    Den[(size_t)th*NPOS + (size_t)b*NS + sblk*128 + s] = v;
  }
}

// ---------------- Kernel C: flash attention, 128s x 192h, 8 waves, pure-MFMA body ----------------
// (identical to the r3-validated 87us kernel, except dfin sums 8 Den partials)
// P and den precomputed by pgen -> body is just {DMA issue, 10 ds_read_b128, 24 MFMA, 1 barrier}.
// Linear grid decoded b = bid%8 so all 64 blocks of one batch share one XCD's L2.
// LDS: sPt 2x8KB + sB 2x24KB + dfin 0.5KB = 64.5 KB -> 2 blocks/CU (essential: the
// co-resident block hides this block's barrier drains; r5 measured 2.5x slowdown at 1/CU).
#define TKC 32

__global__ __launch_bounds__(512, 4) void attn_kernel(
    const unsigned short* __restrict__ ET, const unsigned short* __restrict__ P,
    const float* __restrict__ Den, float* __restrict__ out) {
  int bid  = blockIdx.x;
  int b    = bid & 7;        // same-b blocks land on same XCD
  int r    = bid >> 3;
  int sblk = r & 15;
  int hblk = r >> 4;
  int tid  = threadIdx.x;
  int lane = tid & 63;
  int w    = tid >> 6;       // 0..7

  __shared__ __align__(16) unsigned short sPt[2][4096];   // f16 P tiles
  __shared__ __align__(16) unsigned short sB[2][12288];   // E: hi [0,6144), lo [6144,12288)
  __shared__ float dfin[128];

  const unsigned short* tE = ET + ((size_t)((b*4 + hblk)*64)) * 12288;
  const unsigned short* tP = P + ((size_t)(b*16 + sblk))*64*4096;

  int sh = w & 1, hh = w >> 1;   // wave tile: 64 s x 48 h
  floatx4 acc[4][3];
#pragma unroll
  for (int i = 0; i < 4; i++)
#pragma unroll
    for (int jt = 0; jt < 3; jt++) acc[i][jt] = floatx4{0.f,0.f,0.f,0.f};

  int m16 = lane & 15, q16 = lane >> 4;
  int cidx = (q16 ^ ((m16 >> 1) & 3)) * 8;   // swizzled chunk offset for frag reads
  int t16 = tid * 8;                          // 8 shorts = 16 B per thread per DMA round

  // prologue: den (8 partials) + DMA chunk 0
  if (tid < 128) {
    size_t di = (size_t)b*NS + sblk*128 + tid;
    float d = 0.f;
#pragma unroll
    for (int p = 0; p < 8; p++) d += Den[(size_t)p*NPOS + di];
    dfin[tid] = d;
  }
  GLOAD_LDS16(tE + t16,        &sB[0][0] + t16);
  GLOAD_LDS16(tE + 4096 + t16, &sB[0][0] + 4096 + t16);
  GLOAD_LDS16(tE + 8192 + t16, &sB[0][0] + 8192 + t16);
  GLOAD_LDS16(tP + t16,        &sPt[0][0] + t16);

  for (int ci = 0; ci < 64; ci++) {
    int cb = ci & 1;
    __syncthreads();   // chunk-ci DMA drained; prev MFMA reads retired; dfin visible
    if (ci < 63) {
      const unsigned short* nE = tE + (size_t)(ci+1)*12288;
      const unsigned short* nP = tP + (size_t)(ci+1)*4096;
      unsigned short* sBn = &sB[cb^1][0];
      GLOAD_LDS16(nE + t16,        sBn + t16);
      GLOAD_LDS16(nE + 4096 + t16, sBn + 4096 + t16);
      GLOAD_LDS16(nE + 8192 + t16, sBn + 8192 + t16);
      GLOAD_LDS16(nP + t16,        &sPt[cb^1][0] + t16);
    }
    // MFMA: wave (sh,hh) computes 64x48 via 4x3 tiles of 16x16x32, 2 passes
    const unsigned short* sAc = &sPt[cb][0];
    const unsigned short* sBc = &sB[cb][0];
    half8 a[4];
#pragma unroll
    for (int i = 0; i < 4; i++) {
      int srow = sh*64 + i*16 + m16;
      a[i] = __builtin_bit_cast(half8, *(const uint4*)&sAc[srow*TKC + cidx]);
    }
#pragma unroll
    for (int jt = 0; jt < 3; jt++) {
      int hrow = hh*48 + jt*16 + m16;
      half8 bh_ = __builtin_bit_cast(half8, *(const uint4*)&sBc[hrow*TKC + cidx]);
      half8 bl_ = __builtin_bit_cast(half8, *(const uint4*)&sBc[6144 + hrow*TKC + cidx]);
#pragma unroll
      for (int i = 0; i < 4; i++) {
        acc[i][jt] = __builtin_amdgcn_mfma_f32_16x16x32_f16(a[i], bl_, acc[i][jt], 0, 0, 0);
        acc[i][jt] = __builtin_amdgcn_mfma_f32_16x16x32_f16(a[i], bh_, acc[i][jt], 0, 0, 0);
      }
    }
  }

  // --- epilogue: C/D layout col=lane&15, row=(lane>>4)*4+reg; scale by 1/den ---
  float* ob = out + ((size_t)(b*NS + sblk*128))*NH + hblk*192;
#pragma unroll
  for (int i = 0; i < 4; i++) {
#pragma unroll
    for (int reg = 0; reg < 4; reg++) {
      int row = q16*4 + reg;
      int s_loc = sh*64 + i*16 + row;
      float invd = 1.0f / dfin[s_loc];
#pragma unroll
      for (int jt = 0; jt < 3; jt++) {
        int h_loc = hh*48 + jt*16 + m16;
        ob[(size_t)s_loc*NH + h_loc] = acc[i][jt][reg] * invd;
      }
    }
  }
}

extern "C" void kernel_launch(void* const* d_in, const int* in_sizes, int n_in,
                              void* d_out, int out_size, void* d_ws, size_t ws_size,
                              hipStream_t stream) {
  const float* E   = (const float*)d_in[0];
  const float* Wq  = (const float*)d_in[1];
  const float* bq  = (const float*)d_in[2];
  const float* Wk  = (const float*)d_in[3];
  const float* bk  = (const float*)d_in[4];
  const float* wts = (const float*)d_in[5];
  float* ws  = (float*)d_ws;
  float* Vre = ws;                       // 256 f
  float* Vim = ws + 256;                 // 256 f
  float* Qv  = ws + 512;                 // NPOS*4 f
  float* Kv  = Qv + (size_t)NPOS*4;      // NPOS*4 f
  float* Den = Kv + (size_t)NPOS*4;      // 8*NPOS f (eight th partials)
  unsigned short* ET = (unsigned short*)(Den + (size_t)8*NPOS);        // 50.3 MB
  unsigned short* P  = ET + (size_t)NB*4*64*12288;                     // 67.1 MB
  float* out = (float*)d_out;

  epre_kernel<<<dim3(64, 4, 8), 384, 0, stream>>>(E, wts, Vre, Vim, ET);
  proj_vqc_kernel<<<1024, 256, 0, stream>>>(E, Wq, bq, Wk, bk, Vre, Vim, Qv, Kv);
  pgen_kernel<<<dim3(8, 16, 8), 512, 0, stream>>>(Qv, Kv, P, Den);
  attn_kernel<<<dim3(512), 512, 0, stream>>>(ET, P, Den, out);
}

// Round 7
// 269.665 us; speedup vs baseline: 1.2556x; 1.0291x over previous
//
#include <hip/hip_runtime.h>

#define NB 8
#define NS 2048
#define NH 768
#define NPOS (NB*NS)

typedef _Float16 half8 __attribute__((ext_vector_type(8)));
typedef float floatx4 __attribute__((ext_vector_type(4)));

// async global->LDS, 16B per lane; LDS dest must be wave-uniform base + lane*16
#define GLOAD_LDS16(gp, lp) __builtin_amdgcn_global_load_lds( \
  (const __attribute__((address_space(1))) unsigned int*)(gp), \
  (__attribute__((address_space(3))) unsigned int*)(lp), 16, 0, 0)

// ---------------- Kernel Epre: pre-tile E into swizzled f16 hi/lo tiles ----------------
// Tile (b, hb, tc) = [192 h][32 t], 12288 shorts (24 KB): hi image [0,6144),
// lo image [6144,12288); within each: off = h2*32 + ((q2^((h2>>1)&3))*8).
// f16 split: hi = f16(e) (RTN), lo = f16(e - hi) -> 22-bit effective mantissa.
// Block (0,0,0) threads 0..15 additionally build V = U*diag((-i)^popc) (tiny).
__global__ __launch_bounds__(384) void epre_kernel(
    const float* __restrict__ E, const float* __restrict__ wts,
    float* __restrict__ Vre, float* __restrict__ Vim,
    unsigned short* __restrict__ ET) {
  int tc = blockIdx.x, hb = blockIdx.y, b = blockIdx.z;
  int tid = threadIdx.x;

  if (tc == 0 && hb == 0 && b == 0 && tid < 16) {
    int j = tid;
    float ar[16], ai[16];
#pragma unroll
    for (int i = 0; i < 16; i++) { ar[i] = (i == j) ? 1.f : 0.f; ai[i] = 0.f; }
#pragma unroll
    for (int l = 0; l < 2; l++) {
#pragma unroll
      for (int q = 0; q < 4; q++) {
        float phi = wts[(l*4+q)*3+0];
        float th  = wts[(l*4+q)*3+1];
        float om  = wts[(l*4+q)*3+2];
        float ct = cosf(0.5f*th), st = sinf(0.5f*th);
        float sm = 0.5f*(phi+om), df = 0.5f*(phi-om);
        float cs = cosf(sm), ss = sinf(sm), cd = cosf(df), sd = sinf(df);
        float Ar =  cs*ct, Ai = -ss*ct;
        float Br = -cd*st, Bi = -sd*st;
        float Cr =  cd*st, Ci = -sd*st;
        float Dr =  cs*ct, Di =  ss*ct;
        int pb = 1 << (3-q);
#pragma unroll
        for (int b0 = 0; b0 < 16; b0++) {
          if (b0 & pb) continue;
          int b1 = b0 | pb;
          float xr = ar[b0], xi = ai[b0], yr = ar[b1], yi = ai[b1];
          ar[b0] = Ar*xr - Ai*xi + Br*yr - Bi*yi;
          ai[b0] = Ar*xi + Ai*xr + Br*yi + Bi*yr;
          ar[b1] = Cr*xr - Ci*xi + Dr*yr - Di*yi;
          ai[b1] = Cr*xi + Ci*xr + Dr*yi + Di*yr;
        }
      }
      const int r = (l == 0) ? 1 : 2;
#pragma unroll
      for (int i2 = 0; i2 < 4; i2++) {
        int cb = 1 << (3-i2);
        int tb = 1 << (3-((i2+r)&3));
#pragma unroll
        for (int b0 = 0; b0 < 16; b0++) {
          if ((b0 & cb) && !(b0 & tb)) {
            int b1 = b0 | tb;
            float tr = ar[b0], ti = ai[b0];
            ar[b0] = ar[b1]; ai[b0] = ai[b1];
            ar[b1] = tr;     ai[b1] = ti;
          }
        }
      }
    }
    int pc = __popc((unsigned)j) & 3;
#pragma unroll
    for (int i = 0; i < 16; i++) {
      float vr = ar[i], vi = ai[i], orr, oi;
      if      (pc == 0) { orr =  vr; oi =  vi; }
      else if (pc == 1) { orr =  vi; oi = -vr; }
      else if (pc == 2) { orr = -vr; oi = -vi; }
      else              { orr = -vi; oi =  vr; }
      Vre[i*16+j] = orr;
      Vim[i*16+j] = oi;
    }
  }

  size_t tbase = ((size_t)((b*4 + hb)*64 + tc)) * 12288;
  const float* Eb = E + (size_t)b*NS*NH + (size_t)tc*32*NH + hb*192;
#pragma unroll
  for (int u = 0; u < 2; u++) {
    int unit = tid + 384*u;          // 0..767
    int q2 = unit / 192, h2 = unit % 192;
    unsigned hi4[4], lo4[4];
#pragma unroll
    for (int jp = 0; jp < 4; jp++) {
      float ea = Eb[(size_t)(q2*8 + 2*jp    )*NH + h2];
      float eb = Eb[(size_t)(q2*8 + 2*jp + 1)*NH + h2];
      _Float16 ha = (_Float16)ea, hb16 = (_Float16)eb;
      float la = ea - (float)ha, lb = eb - (float)hb16;
      unsigned uha = __builtin_bit_cast(unsigned short, ha);
      unsigned uhb = __builtin_bit_cast(unsigned short, hb16);
      unsigned ula = __builtin_bit_cast(unsigned short, (_Float16)la);
      unsigned ulb = __builtin_bit_cast(unsigned short, (_Float16)lb);
      hi4[jp] = uha | (uhb << 16);
      lo4[jp] = ula | (ulb << 16);
    }
    int off = h2*32 + ((q2 ^ ((h2>>1)&3))*8);
    *(uint4*)&ET[tbase + off]        = make_uint4(hi4[0],hi4[1],hi4[2],hi4[3]);
    *(uint4*)&ET[tbase + 6144 + off] = make_uint4(lo4[0],lo4[1],lo4[2],lo4[3]);
  }
}

// ---------------- Kernel B: Q/K projection + VQC evaluation ----------------
__global__ __launch_bounds__(256) void proj_vqc_kernel(
    const float* __restrict__ E, const float* __restrict__ Wq, const float* __restrict__ bq,
    const float* __restrict__ Wk, const float* __restrict__ bk,
    const float* __restrict__ Vre, const float* __restrict__ Vim,
    float* __restrict__ Qv, float* __restrict__ Kv) {
  __shared__ __align__(16) float WqL[768*4];
  __shared__ __align__(16) float WkL[768*4];
  __shared__ float Vsh[2][16*17];
  int tid = threadIdx.x;
  for (int idx = tid; idx < 768*4; idx += 256) {
    int e = idx >> 2, w = idx & 3;
    WqL[e*4+w] = Wq[w*768+e];
    WkL[e*4+w] = Wk[w*768+e];
  }
  if (tid < 256) {
    int i = tid >> 4, jj = tid & 15;
    Vsh[0][i*17+jj] = Vre[tid];
    Vsh[1][i*17+jj] = Vim[tid];
  }
  __syncthreads();
  float bqr0=bq[0], bqr1=bq[1], bqr2=bq[2], bqr3=bq[3];
  float bkr0=bk[0], bkr1=bk[1], bkr2=bk[2], bkr3=bk[3];
  int lane = tid & 63;
  int wid  = blockIdx.x*4 + (tid >> 6);
  int nw   = gridDim.x*4;
  int grp  = lane >> 4;
  int i    = lane & 15;
  for (int pos = wid; pos < NPOS; pos += nw) {
    const float* er = E + (size_t)pos*768;
    float pq[4] = {0.f,0.f,0.f,0.f};
    float pk[4] = {0.f,0.f,0.f,0.f};
#pragma unroll
    for (int k2 = 0; k2 < 3; k2++) {
      float4 ev = *(const float4*)(er + lane*4 + 256*k2);
#pragma unroll
      for (int jj = 0; jj < 4; jj++) {
        int e = lane*4 + 256*k2 + jj;
        float evs = (jj==0) ? ev.x : (jj==1) ? ev.y : (jj==2) ? ev.z : ev.w;
        float4 wq4 = *(const float4*)&WqL[e*4];
        float4 wk4 = *(const float4*)&WkL[e*4];
        pq[0] += evs*wq4.x; pq[1] += evs*wq4.y; pq[2] += evs*wq4.z; pq[3] += evs*wq4.w;
        pk[0] += evs*wk4.x; pk[1] += evs*wk4.y; pk[2] += evs*wk4.z; pk[3] += evs*wk4.w;
      }
    }
    float part[8];
#pragma unroll
    for (int w = 0; w < 8; w++) {
      float v = (w < 4) ? pq[w] : pk[w-4];
      v += __shfl_xor(v, 32); v += __shfl_xor(v, 16); v += __shfl_xor(v, 8);
      v += __shfl_xor(v, 4);  v += __shfl_xor(v, 2);  v += __shfl_xor(v, 1);
      part[w] = v;
    }
    if (grp < 2) {
      float a0,a1,a2,a3;
      if (grp == 0) { a0=part[0]+bqr0; a1=part[1]+bqr1; a2=part[2]+bqr2; a3=part[3]+bqr3; }
      else          { a0=part[4]+bkr0; a1=part[5]+bkr1; a2=part[6]+bkr2; a3=part[7]+bkr3; }
      float c0=cosf(0.5f*a0), s0=sinf(0.5f*a0);
      float c1=cosf(0.5f*a1), s1=sinf(0.5f*a1);
      float c2=cosf(0.5f*a2), s2=sinf(0.5f*a2);
      float c3=cosf(0.5f*a3), s3=sinf(0.5f*a3);
      float m[16];
#pragma unroll
      for (int j2 = 0; j2 < 16; j2++) {
        float f0 = (j2 & 8) ? s0 : c0;
        float f1 = (j2 & 4) ? s1 : c1;
        float f2 = (j2 & 2) ? s2 : c2;
        float f3 = (j2 & 1) ? s3 : c3;
        m[j2] = f0*f1*f2*f3;
      }
      float re = 0.f, im = 0.f;
#pragma unroll
      for (int j2 = 0; j2 < 16; j2++) {
        re += Vsh[0][i*17+j2]*m[j2];
        im += Vsh[1][i*17+j2]*m[j2];
      }
      float pr = re*re + im*im;
      float r0 = (i & 8) ? -pr : pr;
      float r1 = (i & 4) ? -pr : pr;
      float r2 = (i & 2) ? -pr : pr;
      float r3 = (i & 1) ? -pr : pr;
#pragma unroll
      for (int off = 8; off >= 1; off >>= 1) {
        r0 += __shfl_xor(r0, off);
        r1 += __shfl_xor(r1, off);
        r2 += __shfl_xor(r2, off);
        r3 += __shfl_xor(r3, off);
      }
      if (i == 0) {
        float* dst = (grp == 0 ? Qv : Kv) + (size_t)pos*4;
        dst[0]=r0; dst[1]=r1; dst[2]=r2; dst[3]=r3;
      }
    }
  }
}

// ---------------- Kernel C: fused attention, 64s x 384h, 8 waves ----------------
// In-kernel P at 2x redundancy (vs r2's 4x) with 2 blocks/CU preserved (r5 lesson:
// never drop to 1 block/CU). Geometry: block = 64s x 384h; 8 waves = 8 h-strips of
// 64s x 48h -> acc stays 4x3 (48 regs). P tile = 64x32 f16 = 4KB (dbuf), only
// 4 exp/thread/chunk. sB holds TWO E tiles (48KB) SINGLE-buffered -> two barriers
// per chunk: DMA(ci) may only start after MFMA(ci-1) retires (bar_A); bar_B drains
// it. Exposed DMA latency is covered by the anti-phase co-resident block (m114).
// Grid 512 = 32 sblk x 2 hp x 8 b; b = bid&7 keeps one batch per XCD (L2-hot ET).
// LDS: sB 48KB + sA 2x4KB + dfin 256B = 57.6KB -> 2 blocks/CU, 16 waves.
#define TKC 32

__global__ __launch_bounds__(512, 4) void attn_kernel(
    const unsigned short* __restrict__ ET, const float* __restrict__ Qv,
    const float* __restrict__ Kv, float* __restrict__ out) {
  int bid  = blockIdx.x;
  int b    = bid & 7;        // same-b blocks land on same XCD
  int r    = bid >> 3;       // 0..63
  int sblk = r & 31;         // 0..31 (64-row s block)
  int hp   = r >> 5;         // 0..1  (covers hb = hp*2, hp*2+1)
  int tid  = threadIdx.x;
  int lane = tid & 63;
  int w    = tid >> 6;       // 0..7

  __shared__ __align__(16) unsigned short sA[2][2048];    // f16 P 64x32, double-buffered
  __shared__ __align__(16) unsigned short sB[24576];      // two E tiles, single-buffered
  __shared__ float dfin[64];

  const unsigned short* tEh = ET + ((size_t)((b*4 + hp*2)*64)) * 12288;

  // ---- P-gen mapping: 512 threads cover 64 s x 8 halves; 4 P values each ----
  int sPg  = tid >> 3;                 // 0..63
  int half = tid & 7;
  int og   = half >> 1;                // physical slot 0..3
  int sub  = half & 1;                 // low/high half of the octet
  int qg   = og ^ ((sPg >> 1) & 3);    // logical t-octet stored at slot og
  int offA = sPg*32 + og*8 + sub*4;
  float4 qv = *(const float4*)&Qv[((size_t)(b*NS + sblk*64) + sPg)*4];
  const float* kvbase = Kv + (size_t)b*NS*4 + (size_t)(qg*8 + sub*4)*4;
  float den_acc = 0.f;

  floatx4 acc[4][3];                   // wave tile: 64 s x 48 h
#pragma unroll
  for (int i = 0; i < 4; i++)
#pragma unroll
    for (int jt = 0; jt < 3; jt++) acc[i][jt] = floatx4{0.f,0.f,0.f,0.f};

  int m16 = lane & 15, q16 = lane >> 4;
  int cidx = (q16 ^ ((m16 >> 1) & 3)) * 8;     // swizzled chunk offset for frag reads
  int t16 = tid * 8;                            // 8 shorts = 16 B per thread per DMA round
  int tileoff = (w >> 2)*12288;                 // which of the two E tiles this wave reads
  int hsub = (w & 3)*48;                        // 48-row strip within the tile

  auto kvload = [&](int ci, float4* kvr) {
    const float* kvp = kvbase + (size_t)ci*128;  // rows ci*32 + qg*8 + sub*4 + j
#pragma unroll
    for (int j = 0; j < 4; j++) kvr[j] = *(const float4*)(kvp + j*4);
  };

  auto pcompute = [&](const float4* kvr) -> uint2 {
    float p[4];
    float dsum = 0.f;
#pragma unroll
    for (int j = 0; j < 4; j++) {
      float4 kk = kvr[j];
      float arg = qv.x*kk.x + qv.y*kk.y + qv.z*kk.z + qv.w*kk.w;
      p[j] = __expf(arg);
      dsum += p[j];
    }
    den_acc += dsum;
    unsigned u0 = (unsigned)__builtin_bit_cast(unsigned short, (_Float16)p[0])
                | ((unsigned)__builtin_bit_cast(unsigned short, (_Float16)p[1]) << 16);
    unsigned u1 = (unsigned)__builtin_bit_cast(unsigned short, (_Float16)p[2])
                | ((unsigned)__builtin_bit_cast(unsigned short, (_Float16)p[3]) << 16);
    return make_uint2(u0, u1);
  };

  auto dma_chunk = [&](int ci) {
    const unsigned short* t0 = tEh + (size_t)ci*12288;   // tile (b, hp*2,   ci)
    const unsigned short* t1 = t0 + (size_t)64*12288;    // tile (b, hp*2+1, ci)
    GLOAD_LDS16(t0 + t16,        sB + t16);
    GLOAD_LDS16(t0 + 4096 + t16, sB + 4096 + t16);
    GLOAD_LDS16(t0 + 8192 + t16, sB + 8192 + t16);
    GLOAD_LDS16(t1 + t16,        sB + 12288 + t16);
    GLOAD_LDS16(t1 + 4096 + t16, sB + 16384 + t16);
    GLOAD_LDS16(t1 + 8192 + t16, sB + 20480 + t16);
  };

  // ---- prologue: DMA E(0); P(0) -> sA[0] ----
  {
    float4 kvr[4];
    kvload(0, kvr);
    dma_chunk(0);
    uint2 ph = pcompute(kvr);
    *(uint2*)&sA[0][offA] = ph;
  }

  // ---- main loop: two barriers per chunk (single-buffered sB) ----
  for (int ci = 0; ci < 64; ci++) {
    int cb = ci & 1;
    uint2 ph;
    if (ci < 63) {                 // P(ci+1) into registers (overlaps prev MFMA tail)
      float4 kvr[4];
      kvload(ci+1, kvr);
      ph = pcompute(kvr);
    }
    __syncthreads();               // bar_A: MFMA(ci-1) retired -> sB/sA[cb^1] reusable
    if (ci > 0) dma_chunk(ci);     // (E(0) DMA'd in prologue)
    if (ci < 63) *(uint2*)&sA[cb^1][offA] = ph;
    __syncthreads();               // bar_B: DMA(ci) drained; sA[cb] visible

    // MFMA: wave w computes 64s x 48h via 4x3 tiles of 16x16x32, 2 passes (E hi+lo)
    const unsigned short* sAc = &sA[cb][0];
    half8 a[4];
#pragma unroll
    for (int i = 0; i < 4; i++) {
      int srow = i*16 + m16;
      a[i] = __builtin_bit_cast(half8, *(const uint4*)&sAc[srow*TKC + cidx]);
    }
#pragma unroll
    for (int jt = 0; jt < 3; jt++) {
      int ro = tileoff + (hsub + jt*16 + m16)*TKC + cidx;
      half8 bh_ = __builtin_bit_cast(half8, *(const uint4*)&sB[ro]);
      half8 bl_ = __builtin_bit_cast(half8, *(const uint4*)&sB[ro + 6144]);
#pragma unroll
      for (int i = 0; i < 4; i++) {
        acc[i][jt] = __builtin_amdgcn_mfma_f32_16x16x32_f16(a[i], bl_, acc[i][jt], 0, 0, 0);
        acc[i][jt] = __builtin_amdgcn_mfma_f32_16x16x32_f16(a[i], bh_, acc[i][jt], 0, 0, 0);
      }
    }
  }

  // --- denominator reduce: 8 "half" lanes per s are contiguous within a wave ---
  {
    float v = den_acc;
    v += __shfl_xor(v, 1);
    v += __shfl_xor(v, 2);
    v += __shfl_xor(v, 4);
    if (half == 0) dfin[sPg] = v;
  }
  __syncthreads();

  // --- epilogue: C/D layout col=lane&15, row=(lane>>4)*4+reg; scale by 1/den ---
  float* ob = out + ((size_t)(b*NS + sblk*64))*NH + hp*384;
#pragma unroll
  for (int i = 0; i < 4; i++) {
#pragma unroll
    for (int reg = 0; reg < 4; reg++) {
      int s_loc = i*16 + q16*4 + reg;
      float invd = 1.0f / dfin[s_loc];
#pragma unroll
      for (int jt = 0; jt < 3; jt++) {
        int h_loc = (w >> 2)*192 + hsub + jt*16 + m16;
        ob[(size_t)s_loc*NH + h_loc] = acc[i][jt][reg] * invd;
      }
    }
  }
}

extern "C" void kernel_launch(void* const* d_in, const int* in_sizes, int n_in,
                              void* d_out, int out_size, void* d_ws, size_t ws_size,
                              hipStream_t stream) {
  const float* E   = (const float*)d_in[0];
  const float* Wq  = (const float*)d_in[1];
  const float* bq  = (const float*)d_in[2];
  const float* Wk  = (const float*)d_in[3];
  const float* bk  = (const float*)d_in[4];
  const float* wts = (const float*)d_in[5];
  float* ws  = (float*)d_ws;
  float* Vre = ws;                       // 256 f
  float* Vim = ws + 256;                 // 256 f
  float* Qv  = ws + 512;                 // NPOS*4 f
  float* Kv  = Qv + (size_t)NPOS*4;      // NPOS*4 f
  unsigned short* ET = (unsigned short*)(Kv + (size_t)NPOS*4);  // 50.3 MB
  float* out = (float*)d_out;

  epre_kernel<<<dim3(64, 4, 8), 384, 0, stream>>>(E, wts, Vre, Vim, ET);
  proj_vqc_kernel<<<1024, 256, 0, stream>>>(E, Wq, bq, Wk, bk, Vre, Vim, Qv, Kv);
  attn_kernel<<<dim3(512), 512, 0, stream>>>(ET, Qv, Kv, out);
}

// Round 9
// 267.775 us; speedup vs baseline: 1.2645x; 1.0071x over previous
//
#include <hip/hip_runtime.h>

#define NB 8
#define NS 2048
#define NH 768
#define NPOS (NB*NS)

typedef _Float16 half8 __attribute__((ext_vector_type(8)));
typedef float floatx4 __attribute__((ext_vector_type(4)));

// async global->LDS, 16B per lane; LDS dest must be wave-uniform base + lane*16
#define GLOAD_LDS16(gp, lp) __builtin_amdgcn_global_load_lds( \
  (const __attribute__((address_space(1))) unsigned int*)(gp), \
  (__attribute__((address_space(3))) unsigned int*)(lp), 16, 0, 0)

// ---------------- Kernel Epre: pre-tile E into swizzled f16 hi/lo tiles ----------------
// r8 layout: tile (b, hp, tc) = 24576 shorts (48 KB):
//   [lo(hb=2hp) 6144][lo(2hp+1) 6144][hi(2hp) 6144][hi(2hp+1) 6144]
// within each 6144-short image: off = h2*32 + ((q2^((h2>>1)&3))*8).
// This makes the attn kernel's per-phase DMA (all-lo or all-hi of both hb) one
// contiguous 24 KB block = 3 x 8 KB rounds.
// f16 split: hi = f16(e) (RTN), lo = f16(e - hi) -> 22-bit effective mantissa.
// Block (0,0,0) threads 0..15 additionally build V = U*diag((-i)^popc) (tiny).
__global__ __launch_bounds__(384) void epre_kernel(
    const float* __restrict__ E, const float* __restrict__ wts,
    float* __restrict__ Vre, float* __restrict__ Vim,
    unsigned short* __restrict__ ET) {
  int tc = blockIdx.x, hb = blockIdx.y, b = blockIdx.z;
  int tid = threadIdx.x;

  if (tc == 0 && hb == 0 && b == 0 && tid < 16) {
    int j = tid;
    float ar[16], ai[16];
#pragma unroll
    for (int i = 0; i < 16; i++) { ar[i] = (i == j) ? 1.f : 0.f; ai[i] = 0.f; }
#pragma unroll
    for (int l = 0; l < 2; l++) {
#pragma unroll
      for (int q = 0; q < 4; q++) {
        float phi = wts[(l*4+q)*3+0];
        float th  = wts[(l*4+q)*3+1];
        float om  = wts[(l*4+q)*3+2];
        float ct = cosf(0.5f*th), st = sinf(0.5f*th);
        float sm = 0.5f*(phi+om), df = 0.5f*(phi-om);
        float cs = cosf(sm), ss = sinf(sm), cd = cosf(df), sd = sinf(df);
        float Ar =  cs*ct, Ai = -ss*ct;
        float Br = -cd*st, Bi = -sd*st;
        float Cr =  cd*st, Ci = -sd*st;
        float Dr =  cs*ct, Di =  ss*ct;
        int pb = 1 << (3-q);
#pragma unroll
        for (int b0 = 0; b0 < 16; b0++) {
          if (b0 & pb) continue;
          int b1 = b0 | pb;
          float xr = ar[b0], xi = ai[b0], yr = ar[b1], yi = ai[b1];
          ar[b0] = Ar*xr - Ai*xi + Br*yr - Bi*yi;
          ai[b0] = Ar*xi + Ai*xr + Br*yi + Bi*yr;
          ar[b1] = Cr*xr - Ci*xi + Dr*yr - Di*yi;
          ai[b1] = Cr*xi + Ci*xr + Dr*yi + Di*yr;
        }
      }
      const int r = (l == 0) ? 1 : 2;
#pragma unroll
      for (int i2 = 0; i2 < 4; i2++) {
        int cb = 1 << (3-i2);
        int tb = 1 << (3-((i2+r)&3));
#pragma unroll
        for (int b0 = 0; b0 < 16; b0++) {
          if ((b0 & cb) && !(b0 & tb)) {
            int b1 = b0 | tb;
            float tr = ar[b0], ti = ai[b0];
            ar[b0] = ar[b1]; ai[b0] = ai[b1];
            ar[b1] = tr;     ai[b1] = ti;
          }
        }
      }
    }
    int pc = __popc((unsigned)j) & 3;
#pragma unroll
    for (int i = 0; i < 16; i++) {
      float vr = ar[i], vi = ai[i], orr, oi;
      if      (pc == 0) { orr =  vr; oi =  vi; }
      else if (pc == 1) { orr =  vi; oi = -vr; }
      else if (pc == 2) { orr = -vr; oi = -vi; }
      else              { orr = -vi; oi =  vr; }
      Vre[i*16+j] = orr;
      Vim[i*16+j] = oi;
    }
  }

  // tile base for (b, hp, tc); this block writes the j = hb&1 images
  size_t tb2 = ((size_t)((b*2 + (hb>>1))*64 + tc)) * 24576 + (size_t)(hb & 1)*6144;
  const float* Eb = E + (size_t)b*NS*NH + (size_t)tc*32*NH + hb*192;
#pragma unroll
  for (int u = 0; u < 2; u++) {
    int unit = tid + 384*u;          // 0..767
    int q2 = unit / 192, h2 = unit % 192;
    unsigned hi4[4], lo4[4];
#pragma unroll
    for (int jp = 0; jp < 4; jp++) {
      float ea = Eb[(size_t)(q2*8 + 2*jp    )*NH + h2];
      float eb = Eb[(size_t)(q2*8 + 2*jp + 1)*NH + h2];
      _Float16 ha = (_Float16)ea, hb16 = (_Float16)eb;
      float la = ea - (float)ha, lb = eb - (float)hb16;
      unsigned uha = __builtin_bit_cast(unsigned short, ha);
      unsigned uhb = __builtin_bit_cast(unsigned short, hb16);
      unsigned ula = __builtin_bit_cast(unsigned short, (_Float16)la);
      unsigned ulb = __builtin_bit_cast(unsigned short, (_Float16)lb);
      hi4[jp] = uha | (uhb << 16);
      lo4[jp] = ula | (ulb << 16);
    }
    int off = h2*32 + ((q2 ^ ((h2>>1)&3))*8);
    *(uint4*)&ET[tb2 + off]         = make_uint4(lo4[0],lo4[1],lo4[2],lo4[3]);  // lo image
    *(uint4*)&ET[tb2 + 12288 + off] = make_uint4(hi4[0],hi4[1],hi4[2],hi4[3]);  // hi image
  }
}

// ---------------- Kernel B: Q/K projection + VQC evaluation ----------------
__global__ __launch_bounds__(256) void proj_vqc_kernel(
    const float* __restrict__ E, const float* __restrict__ Wq, const float* __restrict__ bq,
    const float* __restrict__ Wk, const float* __restrict__ bk,
    const float* __restrict__ Vre, const float* __restrict__ Vim,
    float* __restrict__ Qv, float* __restrict__ Kv) {
  __shared__ __align__(16) float WqL[768*4];
  __shared__ __align__(16) float WkL[768*4];
  __shared__ float Vsh[2][16*17];
  int tid = threadIdx.x;
  for (int idx = tid; idx < 768*4; idx += 256) {
    int e = idx >> 2, w = idx & 3;
    WqL[e*4+w] = Wq[w*768+e];
    WkL[e*4+w] = Wk[w*768+e];
  }
  if (tid < 256) {
    int i = tid >> 4, jj = tid & 15;
    Vsh[0][i*17+jj] = Vre[tid];
    Vsh[1][i*17+jj] = Vim[tid];
  }
  __syncthreads();
  float bqr0=bq[0], bqr1=bq[1], bqr2=bq[2], bqr3=bq[3];
  float bkr0=bk[0], bkr1=bk[1], bkr2=bk[2], bkr3=bk[3];
  int lane = tid & 63;
  int wid  = blockIdx.x*4 + (tid >> 6);
  int nw   = gridDim.x*4;
  int grp  = lane >> 4;
  int i    = lane & 15;
  for (int pos = wid; pos < NPOS; pos += nw) {
    const float* er = E + (size_t)pos*768;
    float pq[4] = {0.f,0.f,0.f,0.f};
    float pk[4] = {0.f,0.f,0.f,0.f};
#pragma unroll
    for (int k2 = 0; k2 < 3; k2++) {
      float4 ev = *(const float4*)(er + lane*4 + 256*k2);
#pragma unroll
      for (int jj = 0; jj < 4; jj++) {
        int e = lane*4 + 256*k2 + jj;
        float evs = (jj==0) ? ev.x : (jj==1) ? ev.y : (jj==2) ? ev.z : ev.w;
        float4 wq4 = *(const float4*)&WqL[e*4];
        float4 wk4 = *(const float4*)&WkL[e*4];
        pq[0] += evs*wq4.x; pq[1] += evs*wq4.y; pq[2] += evs*wq4.z; pq[3] += evs*wq4.w;
        pk[0] += evs*wk4.x; pk[1] += evs*wk4.y; pk[2] += evs*wk4.z; pk[3] += evs*wk4.w;
      }
    }
    float part[8];
#pragma unroll
    for (int w = 0; w < 8; w++) {
      float v = (w < 4) ? pq[w] : pk[w-4];
      v += __shfl_xor(v, 32); v += __shfl_xor(v, 16); v += __shfl_xor(v, 8);
      v += __shfl_xor(v, 4);  v += __shfl_xor(v, 2);  v += __shfl_xor(v, 1);
      part[w] = v;
    }
    if (grp < 2) {
      float a0,a1,a2,a3;
      if (grp == 0) { a0=part[0]+bqr0; a1=part[1]+bqr1; a2=part[2]+bqr2; a3=part[3]+bqr3; }
      else          { a0=part[4]+bkr0; a1=part[5]+bkr1; a2=part[6]+bkr2; a3=part[7]+bkr3; }
      float c0=cosf(0.5f*a0), s0=sinf(0.5f*a0);
      float c1=cosf(0.5f*a1), s1=sinf(0.5f*a1);
      float c2=cosf(0.5f*a2), s2=sinf(0.5f*a2);
      float c3=cosf(0.5f*a3), s3=sinf(0.5f*a3);
      float m[16];
#pragma unroll
      for (int j2 = 0; j2 < 16; j2++) {
        float f0 = (j2 & 8) ? s0 : c0;
        float f1 = (j2 & 4) ? s1 : c1;
        float f2 = (j2 & 2) ? s2 : c2;
        float f3 = (j2 & 1) ? s3 : c3;
        m[j2] = f0*f1*f2*f3;
      }
      float re = 0.f, im = 0.f;
#pragma unroll
      for (int j2 = 0; j2 < 16; j2++) {
        re += Vsh[0][i*17+j2]*m[j2];
        im += Vsh[1][i*17+j2]*m[j2];
      }
      float pr = re*re + im*im;
      float r0 = (i & 8) ? -pr : pr;
      float r1 = (i & 4) ? -pr : pr;
      float r2 = (i & 2) ? -pr : pr;
      float r3 = (i & 1) ? -pr : pr;
#pragma unroll
      for (int off = 8; off >= 1; off >>= 1) {
        r0 += __shfl_xor(r0, off);
        r1 += __shfl_xor(r1, off);
        r2 += __shfl_xor(r2, off);
        r3 += __shfl_xor(r3, off);
      }
      if (i == 0) {
        float* dst = (grp == 0 ? Qv : Kv) + (size_t)pos*4;
        dst[0]=r0; dst[1]=r1; dst[2]=r2; dst[3]=r3;
      }
    }
  }
}

// ---------------- Kernel C: fused attention, 64s x 384h, 8 waves, image-phased ----------------
// r8: per chunk, TWO phases at the hi/lo image granularity so every 24 KB DMA
// drains UNDER an MFMA phase (r7 exposed it between back-to-back barriers):
//   phase A(ci): MFMA x lo(ci) read from sLo   || DMA hi(ci) -> sHi  (drains at bar2)
//   phase B(ci): MFMA x hi(ci) read from sHi   || DMA lo(ci+1) -> sLo (drains at bar1')
// sLo/sHi single-buffered 24 KB each; P at 2x redundancy in dbuf sA (4 exp/thread).
// Per-acc-element order stays (lo then hi) -> bit-identical output vs r2/r7.
// Grid 512 = 32 sblk x 2 hp x 8 b; b = bid&7 keeps one batch per XCD (ET L2-hot,
// FETCH ~25 MB measured in r7). LDS: 24+24+8+0.25 = 56.25 KB -> 2 blocks/CU
// (r5 lesson: the co-resident block is what hides barrier/latency gaps).
#define TKC 32

__global__ __launch_bounds__(512, 4) void attn_kernel(
    const unsigned short* __restrict__ ET, const float* __restrict__ Qv,
    const float* __restrict__ Kv, float* __restrict__ out) {
  int bid  = blockIdx.x;
  int b    = bid & 7;        // same-b blocks land on same XCD
  int r    = bid >> 3;       // 0..63
  int sblk = r & 31;         // 0..31 (64-row s block)
  int hp   = r >> 5;         // 0..1  (covers hb = hp*2, hp*2+1)
  int tid  = threadIdx.x;
  int lane = tid & 63;
  int w    = tid >> 6;       // 0..7

  __shared__ __align__(16) unsigned short sA[2][2048];   // f16 P 64x32, double-buffered
  __shared__ __align__(16) unsigned short sLo[12288];    // lo images [lo_hb0 | lo_hb1]
  __shared__ __align__(16) unsigned short sHi[12288];    // hi images [hi_hb0 | hi_hb1]
  __shared__ float dfin[64];

  const unsigned short* tEh = ET + ((size_t)((b*2 + hp)*64)) * 24576;

  // ---- P-gen mapping: 512 threads cover 64 s x 8 halves; 4 P values each ----
  int sPg  = tid >> 3;                 // 0..63
  int half = tid & 7;
  int og   = half >> 1;                // physical slot 0..3
  int sub  = half & 1;                 // low/high half of the octet
  int qg   = og ^ ((sPg >> 1) & 3);    // logical t-octet stored at slot og
  int offA = sPg*32 + og*8 + sub*4;
  float4 qv = *(const float4*)&Qv[((size_t)(b*NS + sblk*64) + sPg)*4];
  const float* kvbase = Kv + (size_t)b*NS*4 + (size_t)(qg*8 + sub*4)*4;
  float den_acc = 0.f;

  floatx4 acc[4][3];                   // wave tile: 64 s x 48 h
#pragma unroll
  for (int i = 0; i < 4; i++)
#pragma unroll
    for (int jt = 0; jt < 3; jt++) acc[i][jt] = floatx4{0.f,0.f,0.f,0.f};

  int m16 = lane & 15, q16 = lane >> 4;
  int cidx = (q16 ^ ((m16 >> 1) & 3)) * 8;     // swizzled chunk offset for frag reads
  int t16 = tid * 8;                            // 8 shorts = 16 B per thread per DMA round
  int imgoff = (w >> 2)*6144;                   // which hb image this wave reads
  int hsub = (w & 3)*48;                        // 48-row strip within the image

  auto kvload = [&](int ci, float4* kvr) {
    const float* kvp = kvbase + (size_t)ci*128;  // rows ci*32 + qg*8 + sub*4 + j
#pragma unroll
    for (int j = 0; j < 4; j++) kvr[j] = *(const float4*)(kvp + j*4);
  };

  auto pcompute = [&](const float4* kvr) -> uint2 {
    float p[4];
    float dsum = 0.f;
#pragma unroll
    for (int j = 0; j < 4; j++) {
      float4 kk = kvr[j];
      float arg = qv.x*kk.x + qv.y*kk.y + qv.z*kk.z + qv.w*kk.w;
      p[j] = __expf(arg);
      dsum += p[j];
    }
    den_acc += dsum;
    unsigned u0 = (unsigned)__builtin_bit_cast(unsigned short, (_Float16)p[0])
                | ((unsigned)__builtin_bit_cast(unsigned short, (_Float16)p[1]) << 16);
    unsigned u1 = (unsigned)__builtin_bit_cast(unsigned short, (_Float16)p[2])
                | ((unsigned)__builtin_bit_cast(unsigned short, (_Float16)p[3]) << 16);
    return make_uint2(u0, u1);
  };

  // ---- prologue: DMA lo(0); P(0) -> sA[0] ----
  {
    float4 kvr[4];
    kvload(0, kvr);
    const unsigned short* lsrc = tEh;            // lo block of chunk 0
    GLOAD_LDS16(lsrc + t16,        sLo + t16);
    GLOAD_LDS16(lsrc + 4096 + t16, sLo + 4096 + t16);
    GLOAD_LDS16(lsrc + 8192 + t16, sLo + 8192 + t16);
    uint2 ph = pcompute(kvr);
    *(uint2*)&sA[0][offA] = ph;
  }

  for (int ci = 0; ci < 64; ci++) {
    int cb = ci & 1;

    __syncthreads();   // bar1: lo(ci) DMA drained; hi(ci-1) reads retired; sA[cb] visible

    // DMA hi(ci) into sHi (freed at bar1); drains at bar2 under phase-A MFMA
    {
      const unsigned short* hsrc = tEh + (size_t)ci*24576 + 12288;
      GLOAD_LDS16(hsrc + t16,        sHi + t16);
      GLOAD_LDS16(hsrc + 4096 + t16, sHi + 4096 + t16);
      GLOAD_LDS16(hsrc + 8192 + t16, sHi + 8192 + t16);
    }

    uint2 ph;
    if (ci < 63) {                 // P(ci+1): VALU work overlaps phase-A MFMAs
      float4 kvr[4];
      kvload(ci+1, kvr);
      ph = pcompute(kvr);
    }

    // phase A: lo-image MFMAs (a[] frags persist into phase B)
    const unsigned short* sAc = &sA[cb][0];
    half8 a[4];
#pragma unroll
    for (int i = 0; i < 4; i++) {
      int srow = i*16 + m16;
      a[i] = __builtin_bit_cast(half8, *(const uint4*)&sAc[srow*TKC + cidx]);
    }
#pragma unroll
    for (int jt = 0; jt < 3; jt++) {
      int ro = imgoff + (hsub + jt*16 + m16)*TKC + cidx;
      half8 bl_ = __builtin_bit_cast(half8, *(const uint4*)&sLo[ro]);
#pragma unroll
      for (int i = 0; i < 4; i++)
        acc[i][jt] = __builtin_amdgcn_mfma_f32_16x16x32_f16(a[i], bl_, acc[i][jt], 0, 0, 0);
    }
    if (ci < 63) *(uint2*)&sA[cb^1][offA] = ph;   // after bar1 -> safe vs MFMA(ci-1)

    __syncthreads();   // bar2: hi(ci) DMA drained; lo(ci) reads retired

    // DMA lo(ci+1) into sLo (freed at bar2); drains at next bar1 under phase-B MFMA
    if (ci < 63) {
      const unsigned short* lsrc = tEh + (size_t)(ci+1)*24576;
      GLOAD_LDS16(lsrc + t16,        sLo + t16);
      GLOAD_LDS16(lsrc + 4096 + t16, sLo + 4096 + t16);
      GLOAD_LDS16(lsrc + 8192 + t16, sLo + 8192 + t16);
    }

    // phase B: hi-image MFMAs (per-element order lo-then-hi preserved)
#pragma unroll
    for (int jt = 0; jt < 3; jt++) {
      int ro = imgoff + (hsub + jt*16 + m16)*TKC + cidx;
      half8 bh_ = __builtin_bit_cast(half8, *(const uint4*)&sHi[ro]);
#pragma unroll
      for (int i = 0; i < 4; i++)
        acc[i][jt] = __builtin_amdgcn_mfma_f32_16x16x32_f16(a[i], bh_, acc[i][jt], 0, 0, 0);
    }
  }

  // --- denominator reduce: 8 "half" lanes per s are contiguous within a wave ---
  {
    float v = den_acc;
    v += __shfl_xor(v, 1);
    v += __shfl_xor(v, 2);
    v += __shfl_xor(v, 4);
    if (half == 0) dfin[sPg] = v;
  }
  __syncthreads();

  // --- epilogue: C/D layout col=lane&15, row=(lane>>4)*4+reg; scale by 1/den ---
  float* ob = out + ((size_t)(b*NS + sblk*64))*NH + hp*384;
#pragma unroll
  for (int i = 0; i < 4; i++) {
#pragma unroll
    for (int reg = 0; reg < 4; reg++) {
      int s_loc = i*16 + q16*4 + reg;
      float invd = 1.0f / dfin[s_loc];
#pragma unroll
      for (int jt = 0; jt < 3; jt++) {
        int h_loc = (w >> 2)*192 + hsub + jt*16 + m16;
        ob[(size_t)s_loc*NH + h_loc] = acc[i][jt][reg] * invd;
      }
    }
  }
}

extern "C" void kernel_launch(void* const* d_in, const int* in_sizes, int n_in,
                              void* d_out, int out_size, void* d_ws, size_t ws_size,
                              hipStream_t stream) {
  const float* E   = (const float*)d_in[0];
  const float* Wq  = (const float*)d_in[1];
  const float* bq  = (const float*)d_in[2];
  const float* Wk  = (const float*)d_in[3];
  const float* bk  = (const float*)d_in[4];
  const float* wts = (const float*)d_in[5];
  float* ws  = (float*)d_ws;
  float* Vre = ws;                       // 256 f
  float* Vim = ws + 256;                 // 256 f
  float* Qv  = ws + 512;                 // NPOS*4 f
  float* Kv  = Qv + (size_t)NPOS*4;      // NPOS*4 f
  unsigned short* ET = (unsigned short*)(Kv + (size_t)NPOS*4);  // 50.3 MB
  float* out = (float*)d_out;

  epre_kernel<<<dim3(64, 4, 8), 384, 0, stream>>>(E, wts, Vre, Vim, ET);
  proj_vqc_kernel<<<1024, 256, 0, stream>>>(E, Wq, bq, Wk, bk, Vre, Vim, Qv, Kv);
  attn_kernel<<<dim3(512), 512, 0, stream>>>(ET, Qv, Kv, out);
}

// Round 10
// 259.431 us; speedup vs baseline: 1.3052x; 1.0322x over previous
//
#include <hip/hip_runtime.h>

#define NB 8
#define NS 2048
#define NH 768
#define NPOS (NB*NS)

typedef _Float16 half8 __attribute__((ext_vector_type(8)));
typedef float floatx4 __attribute__((ext_vector_type(4)));

// async global->LDS, 16B per lane; LDS dest must be wave-uniform base + lane*16
#define GLOAD_LDS16(gp, lp) __builtin_amdgcn_global_load_lds( \
  (const __attribute__((address_space(1))) unsigned int*)(gp), \
  (__attribute__((address_space(3))) unsigned int*)(lp), 16, 0, 0)

// ---------------- Kernel Epre: pre-tile E into swizzled f16 hi/lo tiles ----------------
// Layout: tile (b, hp, tc) = 24576 shorts (48 KB):
//   [lo(hb=2hp) 6144][lo(2hp+1) 6144][hi(2hp) 6144][hi(2hp+1) 6144]
// within each 6144-short image: off = h2*32 + ((q2^((h2>>1)&3))*8).
// f16 split: hi = f16(e) (RTN), lo = f16(e - hi) -> 22-bit effective mantissa.
// Block (0,0,0) threads 0..15 additionally build V = U*diag((-i)^popc) (tiny).
__global__ __launch_bounds__(384) void epre_kernel(
    const float* __restrict__ E, const float* __restrict__ wts,
    float* __restrict__ Vre, float* __restrict__ Vim,
    unsigned short* __restrict__ ET) {
  int tc = blockIdx.x, hb = blockIdx.y, b = blockIdx.z;
  int tid = threadIdx.x;

  if (tc == 0 && hb == 0 && b == 0 && tid < 16) {
    int j = tid;
    float ar[16], ai[16];
#pragma unroll
    for (int i = 0; i < 16; i++) { ar[i] = (i == j) ? 1.f : 0.f; ai[i] = 0.f; }
#pragma unroll
    for (int l = 0; l < 2; l++) {
#pragma unroll
      for (int q = 0; q < 4; q++) {
        float phi = wts[(l*4+q)*3+0];
        float th  = wts[(l*4+q)*3+1];
        float om  = wts[(l*4+q)*3+2];
        float ct = cosf(0.5f*th), st = sinf(0.5f*th);
        float sm = 0.5f*(phi+om), df = 0.5f*(phi-om);
        float cs = cosf(sm), ss = sinf(sm), cd = cosf(df), sd = sinf(df);
        float Ar =  cs*ct, Ai = -ss*ct;
        float Br = -cd*st, Bi = -sd*st;
        float Cr =  cd*st, Ci = -sd*st;
        float Dr =  cs*ct, Di =  ss*ct;
        int pb = 1 << (3-q);
#pragma unroll
        for (int b0 = 0; b0 < 16; b0++) {
          if (b0 & pb) continue;
          int b1 = b0 | pb;
          float xr = ar[b0], xi = ai[b0], yr = ar[b1], yi = ai[b1];
          ar[b0] = Ar*xr - Ai*xi + Br*yr - Bi*yi;
          ai[b0] = Ar*xi + Ai*xr + Br*yi + Bi*yr;
          ar[b1] = Cr*xr - Ci*xi + Dr*yr - Di*yi;
          ai[b1] = Cr*xi + Ci*xr + Dr*yi + Di*yr;
        }
      }
      const int r = (l == 0) ? 1 : 2;
#pragma unroll
      for (int i2 = 0; i2 < 4; i2++) {
        int cb = 1 << (3-i2);
        int tb = 1 << (3-((i2+r)&3));
#pragma unroll
        for (int b0 = 0; b0 < 16; b0++) {
          if ((b0 & cb) && !(b0 & tb)) {
            int b1 = b0 | tb;
            float tr = ar[b0], ti = ai[b0];
            ar[b0] = ar[b1]; ai[b0] = ai[b1];
            ar[b1] = tr;     ai[b1] = ti;
          }
        }
      }
    }
    int pc = __popc((unsigned)j) & 3;
#pragma unroll
    for (int i = 0; i < 16; i++) {
      float vr = ar[i], vi = ai[i], orr, oi;
      if      (pc == 0) { orr =  vr; oi =  vi; }
      else if (pc == 1) { orr =  vi; oi = -vr; }
      else if (pc == 2) { orr = -vr; oi = -vi; }
      else              { orr = -vi; oi =  vr; }
      Vre[i*16+j] = orr;
      Vim[i*16+j] = oi;
    }
  }

  // tile base for (b, hp, tc); this block writes the j = hb&1 images
  size_t tb2 = ((size_t)((b*2 + (hb>>1))*64 + tc)) * 24576 + (size_t)(hb & 1)*6144;
  const float* Eb = E + (size_t)b*NS*NH + (size_t)tc*32*NH + hb*192;
#pragma unroll
  for (int u = 0; u < 2; u++) {
    int unit = tid + 384*u;          // 0..767
    int q2 = unit / 192, h2 = unit % 192;
    unsigned hi4[4], lo4[4];
#pragma unroll
    for (int jp = 0; jp < 4; jp++) {
      float ea = Eb[(size_t)(q2*8 + 2*jp    )*NH + h2];
      float eb = Eb[(size_t)(q2*8 + 2*jp + 1)*NH + h2];
      _Float16 ha = (_Float16)ea, hb16 = (_Float16)eb;
      float la = ea - (float)ha, lb = eb - (float)hb16;
      unsigned uha = __builtin_bit_cast(unsigned short, ha);
      unsigned uhb = __builtin_bit_cast(unsigned short, hb16);
      unsigned ula = __builtin_bit_cast(unsigned short, (_Float16)la);
      unsigned ulb = __builtin_bit_cast(unsigned short, (_Float16)lb);
      hi4[jp] = uha | (uhb << 16);
      lo4[jp] = ula | (ulb << 16);
    }
    int off = h2*32 + ((q2 ^ ((h2>>1)&3))*8);
    *(uint4*)&ET[tb2 + off]         = make_uint4(lo4[0],lo4[1],lo4[2],lo4[3]);  // lo image
    *(uint4*)&ET[tb2 + 12288 + off] = make_uint4(hi4[0],hi4[1],hi4[2],hi4[3]);  // hi image
  }
}

// ---------------- Kernel B: Q/K projection + VQC evaluation ----------------
__global__ __launch_bounds__(256) void proj_vqc_kernel(
    const float* __restrict__ E, const float* __restrict__ Wq, const float* __restrict__ bq,
    const float* __restrict__ Wk, const float* __restrict__ bk,
    const float* __restrict__ Vre, const float* __restrict__ Vim,
    float* __restrict__ Qv, float* __restrict__ Kv) {
  __shared__ __align__(16) float WqL[768*4];
  __shared__ __align__(16) float WkL[768*4];
  __shared__ float Vsh[2][16*17];
  int tid = threadIdx.x;
  for (int idx = tid; idx < 768*4; idx += 256) {
    int e = idx >> 2, w = idx & 3;
    WqL[e*4+w] = Wq[w*768+e];
    WkL[e*4+w] = Wk[w*768+e];
  }
  if (tid < 256) {
    int i = tid >> 4, jj = tid & 15;
    Vsh[0][i*17+jj] = Vre[tid];
    Vsh[1][i*17+jj] = Vim[tid];
  }
  __syncthreads();
  float bqr0=bq[0], bqr1=bq[1], bqr2=bq[2], bqr3=bq[3];
  float bkr0=bk[0], bkr1=bk[1], bkr2=bk[2], bkr3=bk[3];
  int lane = tid & 63;
  int wid  = blockIdx.x*4 + (tid >> 6);
  int nw   = gridDim.x*4;
  int grp  = lane >> 4;
  int i    = lane & 15;
  for (int pos = wid; pos < NPOS; pos += nw) {
    const float* er = E + (size_t)pos*768;
    float pq[4] = {0.f,0.f,0.f,0.f};
    float pk[4] = {0.f,0.f,0.f,0.f};
#pragma unroll
    for (int k2 = 0; k2 < 3; k2++) {
      float4 ev = *(const float4*)(er + lane*4 + 256*k2);
#pragma unroll
      for (int jj = 0; jj < 4; jj++) {
        int e = lane*4 + 256*k2 + jj;
        float evs = (jj==0) ? ev.x : (jj==1) ? ev.y : (jj==2) ? ev.z : ev.w;
        float4 wq4 = *(const float4*)&WqL[e*4];
        float4 wk4 = *(const float4*)&WkL[e*4];
        pq[0] += evs*wq4.x; pq[1] += evs*wq4.y; pq[2] += evs*wq4.z; pq[3] += evs*wq4.w;
        pk[0] += evs*wk4.x; pk[1] += evs*wk4.y; pk[2] += evs*wk4.z; pk[3] += evs*wk4.w;
      }
    }
    float part[8];
#pragma unroll
    for (int w = 0; w < 8; w++) {
      float v = (w < 4) ? pq[w] : pk[w-4];
      v += __shfl_xor(v, 32); v += __shfl_xor(v, 16); v += __shfl_xor(v, 8);
      v += __shfl_xor(v, 4);  v += __shfl_xor(v, 2);  v += __shfl_xor(v, 1);
      part[w] = v;
    }
    if (grp < 2) {
      float a0,a1,a2,a3;
      if (grp == 0) { a0=part[0]+bqr0; a1=part[1]+bqr1; a2=part[2]+bqr2; a3=part[3]+bqr3; }
      else          { a0=part[4]+bkr0; a1=part[5]+bkr1; a2=part[6]+bkr2; a3=part[7]+bkr3; }
      float c0=cosf(0.5f*a0), s0=sinf(0.5f*a0);
      float c1=cosf(0.5f*a1), s1=sinf(0.5f*a1);
      float c2=cosf(0.5f*a2), s2=sinf(0.5f*a2);
      float c3=cosf(0.5f*a3), s3=sinf(0.5f*a3);
      float m[16];
#pragma unroll
      for (int j2 = 0; j2 < 16; j2++) {
        float f0 = (j2 & 8) ? s0 : c0;
        float f1 = (j2 & 4) ? s1 : c1;
        float f2 = (j2 & 2) ? s2 : c2;
        float f3 = (j2 & 1) ? s3 : c3;
        m[j2] = f0*f1*f2*f3;
      }
      float re = 0.f, im = 0.f;
#pragma unroll
      for (int j2 = 0; j2 < 16; j2++) {
        re += Vsh[0][i*17+j2]*m[j2];
        im += Vsh[1][i*17+j2]*m[j2];
      }
      float pr = re*re + im*im;
      float r0 = (i & 8) ? -pr : pr;
      float r1 = (i & 4) ? -pr : pr;
      float r2 = (i & 2) ? -pr : pr;
      float r3 = (i & 1) ? -pr : pr;
#pragma unroll
      for (int off = 8; off >= 1; off >>= 1) {
        r0 += __shfl_xor(r0, off);
        r1 += __shfl_xor(r1, off);
        r2 += __shfl_xor(r2, off);
        r3 += __shfl_xor(r3, off);
      }
      if (i == 0) {
        float* dst = (grp == 0 ? Qv : Kv) + (size_t)pos*4;
        dst[0]=r0; dst[1]=r1; dst[2]=r2; dst[3]=r3;
      }
    }
  }
}

// ---------------- Kernel C: fused attention, 64s x 384h, 8 waves, image-phased ----------------
// r10: SAME structure as r9 but the body is reordered so NO vmcnt wait precedes an
// MFMA phase. r9's bug: pcompute consumed the youngest loads (kv) right after the
// hi-DMA issue -> compiler must emit vmcnt(0) -> the 24 KB DMA drained fully
// exposed BEFORE phase A. Now:
//   bar1 -> issue kv(ci+1) -> issue hi(ci) DMA -> phase-A MFMA   (kv+DMA fly under A)
//   bar2 (drains both)     -> issue lo(ci+1) DMA -> pcompute (kv already in regs,
//                             ZERO wait) + sA store -> phase-B MFMA (lo DMA under B)
// Every barrier's implicit vmcnt(0) is preceded by a full MFMA phase. Math order
// unchanged -> bit-identical output (absmax 4.88e-4).
// Grid 512 = 32 sblk x 2 hp x 8 b; b = bid&7 keeps one batch per XCD.
// LDS 56.25 KB -> 2 blocks/CU (r5 lesson: co-resident block hides residual gaps).
#define TKC 32

__global__ __launch_bounds__(512, 4) void attn_kernel(
    const unsigned short* __restrict__ ET, const float* __restrict__ Qv,
    const float* __restrict__ Kv, float* __restrict__ out) {
  int bid  = blockIdx.x;
  int b    = bid & 7;        // same-b blocks land on same XCD
  int r    = bid >> 3;       // 0..63
  int sblk = r & 31;         // 0..31 (64-row s block)
  int hp   = r >> 5;         // 0..1  (covers hb = hp*2, hp*2+1)
  int tid  = threadIdx.x;
  int lane = tid & 63;
  int w    = tid >> 6;       // 0..7

  __shared__ __align__(16) unsigned short sA[2][2048];   // f16 P 64x32, double-buffered
  __shared__ __align__(16) unsigned short sLo[12288];    // lo images [lo_hb0 | lo_hb1]
  __shared__ __align__(16) unsigned short sHi[12288];    // hi images [hi_hb0 | hi_hb1]
  __shared__ float dfin[64];

  const unsigned short* tEh = ET + ((size_t)((b*2 + hp)*64)) * 24576;

  // ---- P-gen mapping: 512 threads cover 64 s x 8 halves; 4 P values each ----
  int sPg  = tid >> 3;                 // 0..63
  int half = tid & 7;
  int og   = half >> 1;                // physical slot 0..3
  int sub  = half & 1;                 // low/high half of the octet
  int qg   = og ^ ((sPg >> 1) & 3);    // logical t-octet stored at slot og
  int offA = sPg*32 + og*8 + sub*4;
  float4 qv = *(const float4*)&Qv[((size_t)(b*NS + sblk*64) + sPg)*4];
  const float* kvbase = Kv + (size_t)b*NS*4 + (size_t)(qg*8 + sub*4)*4;
  float den_acc = 0.f;

  floatx4 acc[4][3];                   // wave tile: 64 s x 48 h
#pragma unroll
  for (int i = 0; i < 4; i++)
#pragma unroll
    for (int jt = 0; jt < 3; jt++) acc[i][jt] = floatx4{0.f,0.f,0.f,0.f};

  int m16 = lane & 15, q16 = lane >> 4;
  int cidx = (q16 ^ ((m16 >> 1) & 3)) * 8;     // swizzled chunk offset for frag reads
  int t16 = tid * 8;                            // 8 shorts = 16 B per thread per DMA round
  int imgoff = (w >> 2)*6144;                   // which hb image this wave reads
  int hsub = (w & 3)*48;                        // 48-row strip within the image

  auto kvload = [&](int ci, float4* kvr) {
    const float* kvp = kvbase + (size_t)ci*128;  // rows ci*32 + qg*8 + sub*4 + j
#pragma unroll
    for (int j = 0; j < 4; j++) kvr[j] = *(const float4*)(kvp + j*4);
  };

  auto pcompute = [&](const float4* kvr) -> uint2 {
    float p[4];
    float dsum = 0.f;
#pragma unroll
    for (int j = 0; j < 4; j++) {
      float4 kk = kvr[j];
      float arg = qv.x*kk.x + qv.y*kk.y + qv.z*kk.z + qv.w*kk.w;
      p[j] = __expf(arg);
      dsum += p[j];
    }
    den_acc += dsum;
    unsigned u0 = (unsigned)__builtin_bit_cast(unsigned short, (_Float16)p[0])
                | ((unsigned)__builtin_bit_cast(unsigned short, (_Float16)p[1]) << 16);
    unsigned u1 = (unsigned)__builtin_bit_cast(unsigned short, (_Float16)p[2])
                | ((unsigned)__builtin_bit_cast(unsigned short, (_Float16)p[3]) << 16);
    return make_uint2(u0, u1);
  };

  // ---- prologue: DMA lo(0); P(0) -> sA[0] (one-time exposed kv wait) ----
  {
    float4 kvr[4];
    kvload(0, kvr);
    const unsigned short* lsrc = tEh;            // lo block of chunk 0
    GLOAD_LDS16(lsrc + t16,        sLo + t16);
    GLOAD_LDS16(lsrc + 4096 + t16, sLo + 4096 + t16);
    GLOAD_LDS16(lsrc + 8192 + t16, sLo + 8192 + t16);
    uint2 ph = pcompute(kvr);
    *(uint2*)&sA[0][offA] = ph;
  }

  for (int ci = 0; ci < 64; ci++) {
    int cb = ci & 1;

    __syncthreads();   // bar1: lo(ci) DMA drained; hi(ci-1) reads retired; sA[cb] visible

    // issue kv loads for P(ci+1): consumed only AFTER bar2, whose structural
    // vmcnt(0) retires them -> pcompute needs zero additional wait.
    float4 kvr[4];
    if (ci < 63) kvload(ci+1, kvr);

    // DMA hi(ci) into sHi (freed at bar1); drains at bar2 UNDER phase-A MFMA
    {
      const unsigned short* hsrc = tEh + (size_t)ci*24576 + 12288;
      GLOAD_LDS16(hsrc + t16,        sHi + t16);
      GLOAD_LDS16(hsrc + 4096 + t16, sHi + 4096 + t16);
      GLOAD_LDS16(hsrc + 8192 + t16, sHi + 8192 + t16);
    }

    // phase A: lo-image MFMAs (a[] frags persist into phase B)
    const unsigned short* sAc = &sA[cb][0];
    half8 a[4];
#pragma unroll
    for (int i = 0; i < 4; i++) {
      int srow = i*16 + m16;
      a[i] = __builtin_bit_cast(half8, *(const uint4*)&sAc[srow*TKC + cidx]);
    }
#pragma unroll
    for (int jt = 0; jt < 3; jt++) {
      int ro = imgoff + (hsub + jt*16 + m16)*TKC + cidx;
      half8 bl_ = __builtin_bit_cast(half8, *(const uint4*)&sLo[ro]);
#pragma unroll
      for (int i = 0; i < 4; i++)
        acc[i][jt] = __builtin_amdgcn_mfma_f32_16x16x32_f16(a[i], bl_, acc[i][jt], 0, 0, 0);
    }

    __syncthreads();   // bar2: hi(ci) DMA + kv loads drained; lo(ci) reads retired

    if (ci < 63) {
      // DMA lo(ci+1) into sLo (freed at bar2); drains at next bar1 UNDER
      // pcompute + phase-B MFMA
      const unsigned short* lsrc = tEh + (size_t)(ci+1)*24576;
      GLOAD_LDS16(lsrc + t16,        sLo + t16);
      GLOAD_LDS16(lsrc + 4096 + t16, sLo + 4096 + t16);
      GLOAD_LDS16(lsrc + 8192 + t16, sLo + 8192 + t16);
      // P(ci+1): kv already in registers (retired at bar2) -> no vmcnt wait
      uint2 ph = pcompute(kvr);
      *(uint2*)&sA[cb^1][offA] = ph;   // read after next bar1; two bars since last reader
    }

    // phase B: hi-image MFMAs (per-element order lo-then-hi preserved)
#pragma unroll
    for (int jt = 0; jt < 3; jt++) {
      int ro = imgoff + (hsub + jt*16 + m16)*TKC + cidx;
      half8 bh_ = __builtin_bit_cast(half8, *(const uint4*)&sHi[ro]);
#pragma unroll
      for (int i = 0; i < 4; i++)
        acc[i][jt] = __builtin_amdgcn_mfma_f32_16x16x32_f16(a[i], bh_, acc[i][jt], 0, 0, 0);
    }
  }

  // --- denominator reduce: 8 "half" lanes per s are contiguous within a wave ---
  {
    float v = den_acc;
    v += __shfl_xor(v, 1);
    v += __shfl_xor(v, 2);
    v += __shfl_xor(v, 4);
    if (half == 0) dfin[sPg] = v;
  }
  __syncthreads();

  // --- epilogue: C/D layout col=lane&15, row=(lane>>4)*4+reg; scale by 1/den ---
  float* ob = out + ((size_t)(b*NS + sblk*64))*NH + hp*384;
#pragma unroll
  for (int i = 0; i < 4; i++) {
#pragma unroll
    for (int reg = 0; reg < 4; reg++) {
      int s_loc = i*16 + q16*4 + reg;
      float invd = 1.0f / dfin[s_loc];
#pragma unroll
      for (int jt = 0; jt < 3; jt++) {
        int h_loc = (w >> 2)*192 + hsub + jt*16 + m16;
        ob[(size_t)s_loc*NH + h_loc] = acc[i][jt][reg] * invd;
      }
    }
  }
}

extern "C" void kernel_launch(void* const* d_in, const int* in_sizes, int n_in,
                              void* d_out, int out_size, void* d_ws, size_t ws_size,
                              hipStream_t stream) {
  const float* E   = (const float*)d_in[0];
  const float* Wq  = (const float*)d_in[1];
  const float* bq  = (const float*)d_in[2];
  const float* Wk  = (const float*)d_in[3];
  const float* bk  = (const float*)d_in[4];
  const float* wts = (const float*)d_in[5];
  float* ws  = (float*)d_ws;
  float* Vre = ws;                       // 256 f
  float* Vim = ws + 256;                 // 256 f
  float* Qv  = ws + 512;                 // NPOS*4 f
  float* Kv  = Qv + (size_t)NPOS*4;      // NPOS*4 f
  unsigned short* ET = (unsigned short*)(Kv + (size_t)NPOS*4);  // 50.3 MB
  float* out = (float*)d_out;

  epre_kernel<<<dim3(64, 4, 8), 384, 0, stream>>>(E, wts, Vre, Vim, ET);
  proj_vqc_kernel<<<1024, 256, 0, stream>>>(E, Wq, bq, Wk, bk, Vre, Vim, Qv, Kv);
  attn_kernel<<<dim3(512), 512, 0, stream>>>(ET, Qv, Kv, out);
}